// Round 12
// baseline (1524.079 us; speedup 1.0000x reference)
//
#include <hip/hip_runtime.h>
#include <cstddef>
#include <cstdint>

namespace {

constexpr int H  = 512;
constexpr int V  = 32000;
constexpr int B  = 64;
constexpr int S  = 64;
constexpr int T  = 32;
constexpr int TQ = 32;

typedef unsigned short ushort_t;
typedef __attribute__((ext_vector_type(8))) short bf16x8;
typedef __attribute__((ext_vector_type(4))) short bf16x4;
typedef __attribute__((ext_vector_type(4))) float f32x4;
typedef __attribute__((ext_vector_type(4))) unsigned u32x4;

__device__ __forceinline__ ushort_t f2bf(float f) {
  union { float f; unsigned u; } v; v.f = f;
  return (ushort_t)((v.u + 0x7FFFu + ((v.u >> 16) & 1u)) >> 16);
}

__device__ __forceinline__ float sigm(float x) { return 1.f / (1.f + expf(-x)); }

__device__ __forceinline__ bf16x8 pack8(f32x4 a, f32x4 b) {
  bf16x8 r;
  r[0] = (short)f2bf(a[0]); r[1] = (short)f2bf(a[1]);
  r[2] = (short)f2bf(a[2]); r[3] = (short)f2bf(a[3]);
  r[4] = (short)f2bf(b[0]); r[5] = (short)f2bf(b[1]);
  r[6] = (short)f2bf(b[2]); r[7] = (short)f2bf(b[3]);
  return r;
}

// ---- cross-XCD coherent data movement: sc0 sc1 ONLY (rounds 5-10 proven;
// round-11 ERRATUM: sc0-only polling can read stale caches -> deadlock) ------
__device__ __forceinline__ u32x4 ld16c(const unsigned* p) {
  u32x4 v;
  asm volatile("global_load_dwordx4 %0, %1, off sc0 sc1" : "=v"(v) : "v"(p));
  return v;
}
__device__ __forceinline__ void st4c(unsigned* p, unsigned v) {
  asm volatile("global_store_dword %0, %1, off sc0 sc1" :: "v"(p), "v"(v) : "memory");
}
__device__ __forceinline__ void waitvm0() {
  asm volatile("s_waitcnt vmcnt(0)" ::: "memory");
  __builtin_amdgcn_sched_barrier(0);
}

// ---------------------------------------------------------------------------
// Embedding + positional encoding
// ---------------------------------------------------------------------------
__global__ __launch_bounds__(256) void k_embed_facts(const int* __restrict__ ctx,
                                                     const float* __restrict__ emb,
                                                     float* __restrict__ facts_in) {
  const int bs = blockIdx.x;
  const int s  = bs & (S - 1);
  const int t  = threadIdx.x;
  __shared__ int sidx[T];
  if (t < T) sidx[t] = ctx[(size_t)bs * T + t];
  __syncthreads();
  float a0 = 0.f, a1 = 0.f;
  for (int tt = 0; tt < T; ++tt) {
    const int ix = sidx[tt];
    if (ix != 0) {
      const float* e = emb + ((size_t)ix << 9);
      a0 += e[t];
      a1 += e[t + 256];
    }
  }
  const float sf = (float)s * (1.f / 64.f);
  const float c1 = 1.f - sf;
  const float c2 = (1.f - 2.f * sf) * (1.f / 512.f);
  facts_in[((size_t)bs << 9) + t]       = a0 * (c1 - (float)t * c2);
  facts_in[((size_t)bs << 9) + t + 256] = a1 * (c1 - (float)(t + 256) * c2);
}

__global__ __launch_bounds__(256) void k_embed_q(const int* __restrict__ qidx,
                                                 const float* __restrict__ emb,
                                                 float* __restrict__ qe) {
  const int bt = blockIdx.x;
  const int t  = threadIdx.x;
  const int ix = qidx[bt];
  float v0 = 0.f, v1 = 0.f;
  if (ix != 0) {
    const float* e = emb + ((size_t)ix << 9);
    v0 = e[t];
    v1 = e[t + 256];
  }
  qe[((size_t)bt << 9) + t]       = v0;
  qe[((size_t)bt << 9) + t + 256] = v1;
}

__global__ __launch_bounds__(256) void k_transpose512(const float* __restrict__ src,
                                                      float* __restrict__ dst) {
  __shared__ float tile[32][33];
  const int x0 = blockIdx.x * 32, y0 = blockIdx.y * 32;
  for (int i = threadIdx.y; i < 32; i += 8)
    tile[i][threadIdx.x] = src[(size_t)(y0 + i) * H + x0 + threadIdx.x];
  __syncthreads();
  for (int i = threadIdx.y; i < 32; i += 8)
    dst[(size_t)(x0 + i) * H + y0 + threadIdx.x] = tile[threadIdx.x][i];
}

// ---------------------------------------------------------------------------
// bf16 MFMA GEMM (NT), round-2/8 proven. A: bf16 (A_BF16) or f32.
// ---------------------------------------------------------------------------
template <bool A_BF16, int ACT>
__global__ __launch_bounds__(256) void k_gemm_mfma(const void* __restrict__ Av,
                                                   const float* __restrict__ Bm,
                                                   const float* __restrict__ bias,
                                                   float* __restrict__ C,
                                                   int M, int N, int K) {
  __shared__ __align__(16) ushort_t As[64][72];
  __shared__ __align__(16) ushort_t Bs[64][72];
  const int t    = threadIdx.x;
  const int lane = t & 63;
  const int w    = t >> 6;
  const int wr   = w >> 1, wc = w & 1;
  const int m0 = blockIdx.y << 6, n0 = blockIdx.x << 6;
  const int row = t >> 2;
  const int ch  = t & 3;

  f32x4 acc[2][2] = {};

  for (int k0 = 0; k0 < K; k0 += 64) {
    if (A_BF16) {
      const ushort_t* A16 = (const ushort_t*)Av;
#pragma unroll
      for (int cc = 0; cc < 2; ++cc) {
        const int c8 = ch + cc * 4;
        const uint4 v = *(const uint4*)(A16 + (size_t)(m0 + row) * K + k0 + c8 * 8);
        *(uint4*)&As[row][c8 * 8] = v;
      }
    } else {
      const float* Af = (const float*)Av;
#pragma unroll
      for (int cc = 0; cc < 2; ++cc) {
        const int c8 = ch + cc * 4;
        const float* src = Af + (size_t)(m0 + row) * K + k0 + c8 * 8;
        *(bf16x8*)&As[row][c8 * 8] = pack8(*(const f32x4*)src, *(const f32x4*)(src + 4));
      }
    }
#pragma unroll
    for (int cc = 0; cc < 2; ++cc) {
      const int c8 = ch + cc * 4;
      const float* srb = Bm + (size_t)(n0 + row) * K + k0 + c8 * 8;
      *(bf16x8*)&Bs[row][c8 * 8] = pack8(*(const f32x4*)srb, *(const f32x4*)(srb + 4));
    }
    __syncthreads();
#pragma unroll
    for (int ks = 0; ks < 2; ++ks) {
      bf16x8 a[2], b[2];
#pragma unroll
      for (int fr = 0; fr < 2; ++fr)
        a[fr] = *(const bf16x8*)&As[wr * 32 + fr * 16 + (lane & 15)][ks * 32 + (lane >> 4) * 8];
#pragma unroll
      for (int fc = 0; fc < 2; ++fc)
        b[fc] = *(const bf16x8*)&Bs[wc * 32 + fc * 16 + (lane & 15)][ks * 32 + (lane >> 4) * 8];
#pragma unroll
      for (int fr = 0; fr < 2; ++fr)
#pragma unroll
        for (int fc = 0; fc < 2; ++fc)
          acc[fr][fc] = __builtin_amdgcn_mfma_f32_16x16x32_bf16(a[fr], b[fc], acc[fr][fc], 0, 0, 0);
    }
    __syncthreads();
  }
#pragma unroll
  for (int fr = 0; fr < 2; ++fr) {
#pragma unroll
    for (int fc = 0; fc < 2; ++fc) {
      const int rbase = m0 + wr * 32 + fr * 16 + ((lane >> 4) << 2);
      const int col   = n0 + wc * 32 + fc * 16 + (lane & 15);
      const float bv  = bias ? bias[col] : 0.f;
#pragma unroll
      for (int j = 0; j < 4; ++j) {
        float v = acc[fr][fc][j] + bv;
        if (ACT == 1) v = tanhf(v);
        if (ACT == 2) v = fmaxf(v, 0.f);
        C[(size_t)(rbase + j) * N + col] = v;
      }
    }
  }
}

// z (bf16) = [f*q, f*M, |f-q|, |f-M|]
__global__ __launch_bounds__(256) void k_build_z16(const float* __restrict__ facts,
                                                   const float* __restrict__ q,
                                                   const float* __restrict__ M,
                                                   ushort_t* __restrict__ z) {
  const int bs = blockIdx.x;
  const int b  = bs >> 6;
  const int t  = threadIdx.x;
  const size_t zb = (size_t)bs << 11;
  for (int c = t; c < 512; c += 256) {
    const float f  = facts[((size_t)bs << 9) + c];
    const float qv = q[(b << 9) + c];
    const float mv = M[(b << 9) + c];
    z[zb + c]        = f2bf(f * qv);
    z[zb + 512 + c]  = f2bf(f * mv);
    z[zb + 1024 + c] = f2bf(fabsf(f - qv));
    z[zb + 1536 + c] = f2bf(fabsf(f - mv));
  }
}

// ---------------------------------------------------------------------------
// nm GEMM with fused concat3: A[64][1536] = [M | C | q]. relu.
// ---------------------------------------------------------------------------
__global__ __launch_bounds__(256) void k_gemm_cat3(const float* __restrict__ Mv,
                                                   const float* __restrict__ Cv,
                                                   const float* __restrict__ qv,
                                                   const float* __restrict__ Bm,
                                                   const float* __restrict__ bias,
                                                   float* __restrict__ C) {
  constexpr int N = 512, K = 1536;
  __shared__ __align__(16) ushort_t As[64][72];
  __shared__ __align__(16) ushort_t Bs[64][72];
  const int t    = threadIdx.x;
  const int lane = t & 63;
  const int w    = t >> 6;
  const int wr   = w >> 1, wc = w & 1;
  const int n0 = blockIdx.x << 6;
  const int row = t >> 2;
  const int ch  = t & 3;

  f32x4 acc[2][2] = {};

  for (int k0 = 0; k0 < K; k0 += 64) {
    const int seg = k0 >> 9;
    const float* src = (seg == 0) ? Mv : (seg == 1) ? Cv : qv;
    const int kb = k0 & 511;
#pragma unroll
    for (int cc = 0; cc < 2; ++cc) {
      const int c8 = ch + cc * 4;
      const float* fp = src + ((size_t)row << 9) + kb + c8 * 8;
      *(bf16x8*)&As[row][c8 * 8] = pack8(*(const f32x4*)fp, *(const f32x4*)(fp + 4));
      const float* srb = Bm + (size_t)(n0 + row) * K + k0 + c8 * 8;
      *(bf16x8*)&Bs[row][c8 * 8] = pack8(*(const f32x4*)srb, *(const f32x4*)(srb + 4));
    }
    __syncthreads();
#pragma unroll
    for (int ks = 0; ks < 2; ++ks) {
      bf16x8 a[2], bb[2];
#pragma unroll
      for (int fr = 0; fr < 2; ++fr)
        a[fr] = *(const bf16x8*)&As[wr * 32 + fr * 16 + (lane & 15)][ks * 32 + (lane >> 4) * 8];
#pragma unroll
      for (int fc = 0; fc < 2; ++fc)
        bb[fc] = *(const bf16x8*)&Bs[wc * 32 + fc * 16 + (lane & 15)][ks * 32 + (lane >> 4) * 8];
#pragma unroll
      for (int fr = 0; fr < 2; ++fr)
#pragma unroll
        for (int fc = 0; fc < 2; ++fc)
          acc[fr][fc] = __builtin_amdgcn_mfma_f32_16x16x32_bf16(a[fr], bb[fc], acc[fr][fc], 0, 0, 0);
    }
    __syncthreads();
  }
#pragma unroll
  for (int fr = 0; fr < 2; ++fr) {
#pragma unroll
    for (int fc = 0; fc < 2; ++fc) {
      const int rbase = wr * 32 + fr * 16 + ((lane >> 4) << 2);
      const int col   = n0 + wc * 32 + fc * 16 + (lane & 15);
      const float bv  = bias[col];
#pragma unroll
      for (int j = 0; j < 4; ++j)
        C[(size_t)(rbase + j) * N + col] = fmaxf(acc[fr][fc][j] + bv, 0.f);
    }
  }
}

// ---------------------------------------------------------------------------
// answer GEMM with fused concat2: A[64][1024] = [M | q]. N=32000.
// ---------------------------------------------------------------------------
__global__ __launch_bounds__(256) void k_gemm_cat2(const float* __restrict__ Mv,
                                                   const float* __restrict__ qv,
                                                   const float* __restrict__ Bm,
                                                   const float* __restrict__ bias,
                                                   float* __restrict__ C) {
  constexpr int N = 32000, K = 1024;
  __shared__ __align__(16) ushort_t As[64][72];
  __shared__ __align__(16) ushort_t Bs[64][72];
  const int t    = threadIdx.x;
  const int lane = t & 63;
  const int w    = t >> 6;
  const int wr   = w >> 1, wc = w & 1;
  const int n0 = blockIdx.x << 6;
  const int row = t >> 2;
  const int ch  = t & 3;

  f32x4 acc[2][2] = {};

  for (int k0 = 0; k0 < K; k0 += 64) {
    const float* src = (k0 < 512) ? Mv : qv;
    const int kb = k0 & 511;
#pragma unroll
    for (int cc = 0; cc < 2; ++cc) {
      const int c8 = ch + cc * 4;
      const float* fp = src + ((size_t)row << 9) + kb + c8 * 8;
      *(bf16x8*)&As[row][c8 * 8] = pack8(*(const f32x4*)fp, *(const f32x4*)(fp + 4));
      const float* srb = Bm + (size_t)(n0 + row) * K + k0 + c8 * 8;
      *(bf16x8*)&Bs[row][c8 * 8] = pack8(*(const f32x4*)srb, *(const f32x4*)(srb + 4));
    }
    __syncthreads();
#pragma unroll
    for (int ks = 0; ks < 2; ++ks) {
      bf16x8 a[2], bb[2];
#pragma unroll
      for (int fr = 0; fr < 2; ++fr)
        a[fr] = *(const bf16x8*)&As[wr * 32 + fr * 16 + (lane & 15)][ks * 32 + (lane >> 4) * 8];
#pragma unroll
      for (int fc = 0; fc < 2; ++fc)
        bb[fc] = *(const bf16x8*)&Bs[wc * 32 + fc * 16 + (lane & 15)][ks * 32 + (lane >> 4) * 8];
#pragma unroll
      for (int fr = 0; fr < 2; ++fr)
#pragma unroll
        for (int fc = 0; fc < 2; ++fc)
          acc[fr][fc] = __builtin_amdgcn_mfma_f32_16x16x32_bf16(a[fr], bb[fc], acc[fr][fc], 0, 0, 0);
    }
    __syncthreads();
  }
#pragma unroll
  for (int fr = 0; fr < 2; ++fr) {
#pragma unroll
    for (int fc = 0; fc < 2; ++fc) {
      const int rbase = wr * 32 + fr * 16 + ((lane >> 4) << 2);
      const int col   = n0 + wc * 32 + fc * 16 + (lane & 15);
      const float bv  = bias[col];
#pragma unroll
      for (int j = 0; j < 4; ++j)
        C[(size_t)(rbase + j) * N + col] = acc[fr][fc][j] + bv;
    }
  }
}

// ---------------------------------------------------------------------------
// Tagged-exchange staging (round-12): the exchange buffer holds dwords
// (bf16 value << 16) | step_tag, written by single atomic dword stores.
// Consumer polls the data directly — no flags, no producer vmcnt drain.
// Deadlock-free: tags are monotone; a producer can only overwrite step-s
// data after passing its step-s+1 poll, which needs every member done with s.
// ---------------------------------------------------------------------------
__device__ __forceinline__ void stage_tagged(const unsigned* __restrict__ buf,
                                             unsigned want, int rows0, int t,
                                             ushort_t* __restrict__ lds) {
  const int item = t >> 4;
  const int colb = (t & 15) << 5;
  const unsigned* base = buf + ((size_t)(rows0 + item) << 9) + colb;
  u32x4 q0, q1, q2, q3, q4, q5, q6, q7;
  unsigned pend = 0xFFu;
  for (;;) {
    if (pend & 0x01u) q0 = ld16c(base + 0);
    if (pend & 0x02u) q1 = ld16c(base + 4);
    if (pend & 0x04u) q2 = ld16c(base + 8);
    if (pend & 0x08u) q3 = ld16c(base + 12);
    if (pend & 0x10u) q4 = ld16c(base + 16);
    if (pend & 0x20u) q5 = ld16c(base + 20);
    if (pend & 0x40u) q6 = ld16c(base + 24);
    if (pend & 0x80u) q7 = ld16c(base + 28);
    waitvm0();
    unsigned np = 0;
#define CHK(qq, bit, off)                                                       \
    if (pend & bit) {                                                           \
      if (((qq[0] & 0xFFFFu) == want) && ((qq[1] & 0xFFFFu) == want) &&         \
          ((qq[2] & 0xFFFFu) == want) && ((qq[3] & 0xFFFFu) == want)) {         \
        bf16x4 r;                                                               \
        r[0] = (short)(qq[0] >> 16); r[1] = (short)(qq[1] >> 16);               \
        r[2] = (short)(qq[2] >> 16); r[3] = (short)(qq[3] >> 16);               \
        *(bf16x4*)&lds[item * 520 + colb + off] = r;                            \
      } else np |= bit;                                                         \
    }
    CHK(q0, 0x01u, 0)  CHK(q1, 0x02u, 4)  CHK(q2, 0x04u, 8)  CHK(q3, 0x08u, 12)
    CHK(q4, 0x10u, 16) CHK(q5, 0x20u, 20) CHK(q6, 0x40u, 24) CHK(q7, 0x80u, 28)
#undef CHK
    pend = np;
    if (!pend) break;
    __builtin_amdgcn_s_sleep(4);
  }
}

// ---------------------------------------------------------------------------
// MFMA persistent GRU scan, round-12: tagged exchange, f32 carry in regs.
// 96 WGs = 12 groups (3 gru x 4 ib of 16 items) x 8. Plain launch.
// ---------------------------------------------------------------------------
__global__ __launch_bounds__(256, 1) void k_gru_scan_mfma(
    const float* __restrict__ Whh_f, const float* __restrict__ bhh_f,
    const float* __restrict__ Whh_b, const float* __restrict__ bhh_b,
    const float* __restrict__ qWhh,  const float* __restrict__ qbhh,
    const float* __restrict__ gx_f, const float* __restrict__ gx_b,
    const float* __restrict__ gx_q,
    unsigned* __restrict__ Hg, float* __restrict__ qbuf,
    float* __restrict__ facts, float* __restrict__ hb_all) {
  const int bx   = blockIdx.x;     // 96
  const int grp  = bx >> 3;        // 0..11
  const int rank = bx & 7;
  const int gru  = grp >> 2;
  const int ib   = grp & 3;        // 16 items each

  const float* Whh; const float* bhh; const float* gx;
  float* out_seq; int seqlen, rev;
  if (gru == 0)      { Whh = Whh_f; bhh = bhh_f; gx = gx_f; out_seq = facts;   seqlen = S;  rev = 0; }
  else if (gru == 1) { Whh = Whh_b; bhh = bhh_b; gx = gx_b; out_seq = hb_all;  seqlen = S;  rev = 1; }
  else               { Whh = qWhh;  bhh = qbhh;  gx = gx_q; out_seq = nullptr; seqlen = TQ; rev = 0; }
  unsigned* Hg0 = Hg + gru * 65536;   // [64][512] tagged dwords, parity 0
  unsigned* Hg1 = Hg0 + 32768;

  __shared__ __align__(16) ushort_t hl[16 * 520];

  const int t    = threadIdx.x;
  const int lane = t & 63;
  const int wv   = t >> 6;
  const int nt   = (rank << 2) + wv;   // 0..31
  const int lm   = lane & 15;
  const int lk   = lane >> 4;          // 0..3
  const int col  = (nt << 4) + lm;

  // pack weight B-fragments once
  bf16x8 wf[3][16];
#pragma unroll
  for (int g = 0; g < 3; ++g) {
    const float* wrow = Whh + ((size_t)(g * 512 + col) << 9) + (lk << 3);
#pragma unroll
    for (int ks = 0; ks < 16; ++ks) {
      const float* p = wrow + ks * 32;
      wf[g][ks] = pack8(*(const f32x4*)p, *(const f32x4*)(p + 4));
    }
  }
  const float bv0 = bhh[col], bv1 = bhh[512 + col], bv2 = bhh[1024 + col];

  float hp[4] = {0.f, 0.f, 0.f, 0.f};   // f32 carry, register-resident

  for (int s = 0; s < seqlen; ++s) {
    // issue gx loads first; they drain under the staging poll
    const int xidx = rev ? (seqlen - 1 - s) : s;
    float xr[4], xz[4], xn[4];
#pragma unroll
    for (int j = 0; j < 4; ++j) {
      const int b = (ib << 4) + (lk << 2) + j;
      const size_t gxrow = ((size_t)b * seqlen + xidx) * 1536;
      xr[j] = gx[gxrow + col];
      xz[j] = gx[gxrow + 512 + col];
      xn[j] = gx[gxrow + 1024 + col];
    }

    if (s == 0) {
      for (int i = t; i < 4160; i += 256) ((unsigned*)hl)[i] = 0u;
    } else {
      const unsigned* Hp = (s & 1) ? Hg1 : Hg0;
      stage_tagged(Hp, (unsigned)s, ib << 4, t, hl);
    }
    __syncthreads();

    f32x4 acc0 = {}, acc1 = {}, acc2 = {};
#pragma unroll
    for (int ks = 0; ks < 16; ++ks) {
      const bf16x8 a = *(const bf16x8*)&hl[lm * 520 + (ks << 5) + (lk << 3)];
      acc0 = __builtin_amdgcn_mfma_f32_16x16x32_bf16(a, wf[0][ks], acc0, 0, 0, 0);
      acc1 = __builtin_amdgcn_mfma_f32_16x16x32_bf16(a, wf[1][ks], acc1, 0, 0, 0);
      acc2 = __builtin_amdgcn_mfma_f32_16x16x32_bf16(a, wf[2][ks], acc2, 0, 0, 0);
    }

    unsigned* Hn = (s & 1) ? Hg0 : Hg1;
#pragma unroll
    for (int j = 0; j < 4; ++j) {
      const int b = (ib << 4) + (lk << 2) + j;
      const float r = sigm(xr[j] + acc0[j] + bv0);
      const float z = sigm(xz[j] + acc1[j] + bv1);
      const float n = tanhf(xn[j] + r * (acc2[j] + bv2));
      const float hnew = (1.f - z) * n + z * hp[j];
      hp[j] = hnew;
      if (s + 1 < seqlen)
        st4c(Hn + ((size_t)b << 9) + col,
             ((unsigned)f2bf(hnew) << 16) | (unsigned)(s + 1));   // fire & forget
      if (out_seq) out_seq[((size_t)(b * S + xidx) << 9) + col] = hnew;
      if (gru == 2 && s == seqlen - 1) qbuf[((size_t)b << 9) + col] = hnew;
    }
    __syncthreads();   // protect hl for next iteration's staging
  }
}

// ---------------------------------------------------------------------------
// MFMA persistent AGRU scan, round-12: tagged exchange (monotone tags via
// tagbase = hop*64). 32 WGs = 4 groups x 8. Plain launch.
// ---------------------------------------------------------------------------
__global__ __launch_bounds__(256, 1) void k_agru_scan_mfma(
    const float* __restrict__ UrT, const float* __restrict__ UT,
    const float* __restrict__ fRW, const float* __restrict__ fW,
    const float* __restrict__ br, const float* __restrict__ G,
    unsigned* __restrict__ Ct, float* __restrict__ C0f, int tagbase) {
  const int bx   = blockIdx.x;     // 32
  const int grp  = bx >> 3;        // 0..3 (16 items each)
  const int rank = bx & 7;
  unsigned* Ct0 = Ct;
  unsigned* Ct1 = Ct + 32768;

  __shared__ __align__(16) ushort_t cl[16 * 520];

  const int t    = threadIdx.x;
  const int lane = t & 63;
  const int wv   = t >> 6;
  const int nt   = (rank << 2) + wv;
  const int lm   = lane & 15;
  const int lk   = lane >> 4;
  const int col  = (nt << 4) + lm;

  bf16x8 wfr[16], wfu[16];
  {
    const float* r0 = UrT + ((size_t)col << 9) + (lk << 3);
    const float* r1 = UT  + ((size_t)col << 9) + (lk << 3);
#pragma unroll
    for (int ks = 0; ks < 16; ++ks) {
      wfr[ks] = pack8(*(const f32x4*)(r0 + ks * 32), *(const f32x4*)(r0 + ks * 32 + 4));
      wfu[ks] = pack8(*(const f32x4*)(r1 + ks * 32), *(const f32x4*)(r1 + ks * 32 + 4));
    }
  }
  const float brv = br[col];

  float cp[4] = {0.f, 0.f, 0.f, 0.f};

  for (int s = 0; s < S; ++s) {
    float fr[4], fw[4], gg[4];
#pragma unroll
    for (int j = 0; j < 4; ++j) {
      const int b = (grp << 4) + (lk << 2) + j;
      const size_t fi = ((size_t)(b * S + s) << 9) + col;
      fr[j] = fRW[fi];
      fw[j] = fW[fi];
      gg[j] = G[(b << 6) + s];
    }

    if (s == 0) {
      for (int i = t; i < 4160; i += 256) ((unsigned*)cl)[i] = 0u;
    } else {
      const unsigned* Cp = (s & 1) ? Ct1 : Ct0;
      stage_tagged(Cp, (unsigned)(tagbase + s), grp << 4, t, cl);
    }
    __syncthreads();

    f32x4 accr = {}, accu = {};
#pragma unroll
    for (int ks = 0; ks < 16; ++ks) {
      const bf16x8 a = *(const bf16x8*)&cl[lm * 520 + (ks << 5) + (lk << 3)];
      accr = __builtin_amdgcn_mfma_f32_16x16x32_bf16(a, wfr[ks], accr, 0, 0, 0);
      accu = __builtin_amdgcn_mfma_f32_16x16x32_bf16(a, wfu[ks], accu, 0, 0, 0);
    }

    unsigned* Cn = (s & 1) ? Ct0 : Ct1;
#pragma unroll
    for (int j = 0; j < 4; ++j) {
      const int b = (grp << 4) + (lk << 2) + j;
      const float r  = sigm(fr[j] + accr[j] + brv);
      const float ht = tanhf(fw[j] + r * accu[j] + brv);
      const float cnew = gg[j] * ht + (1.f - gg[j]) * cp[j];
      cp[j] = cnew;
      if (s + 1 < S)
        st4c(Cn + ((size_t)b << 9) + col,
             ((unsigned)f2bf(cnew) << 16) | (unsigned)(tagbase + s + 1));
      else
        C0f[((size_t)b << 9) + col] = cnew;
    }
    __syncthreads();
  }
}

__global__ __launch_bounds__(256) void k_add(float* __restrict__ a, const float* __restrict__ b) {
  const size_t i = (((size_t)blockIdx.x << 8) + threadIdx.x) << 2;
  float4 x = *(float4*)(a + i);
  const float4 y = *(const float4*)(b + i);
  x.x += y.x; x.y += y.y; x.z += y.z; x.w += y.w;
  *(float4*)(a + i) = x;
}

__global__ __launch_bounds__(256) void k_score_softmax(const float* __restrict__ g1,
                                                       const float* __restrict__ z2w,
                                                       const float* __restrict__ z2b,
                                                       float* __restrict__ G) {
  const int b = blockIdx.x, t = threadIdx.x;
  const int wave = t >> 6, lane = t & 63;
  __shared__ float sc[64];
  for (int si = 0; si < 16; ++si) {
    const int s = wave * 16 + si;
    const float* row = g1 + ((size_t)(b * S + s) << 9) + lane * 8;
    const float* w   = z2w + lane * 8;
    float p = 0.f;
#pragma unroll
    for (int k = 0; k < 8; ++k) p += row[k] * w[k];
#pragma unroll
    for (int off = 32; off; off >>= 1) p += __shfl_xor(p, off);
    if (lane == 0) sc[s] = p + z2b[0];
  }
  __syncthreads();
  if (wave == 0) {
    const float v = sc[lane];
    float m = v;
#pragma unroll
    for (int off = 32; off; off >>= 1) m = fmaxf(m, __shfl_xor(m, off));
    const float e = expf(v - m);
    float su = e;
#pragma unroll
    for (int off = 32; off; off >>= 1) su += __shfl_xor(su, off);
    G[(b << 6) + lane] = e / su;
  }
}

}  // namespace

extern "C" void kernel_launch(void* const* d_in, const int* in_sizes, int n_in,
                              void* d_out, int out_size, void* d_ws, size_t ws_size,
                              hipStream_t stream) {
  const int*   contexts  = (const int*)d_in[0];
  const int*   questions = (const int*)d_in[1];
  const float* emb   = (const float*)d_in[2];
  const float* Wih_f = (const float*)d_in[3];
  const float* Whh_f = (const float*)d_in[4];
  const float* bih_f = (const float*)d_in[5];
  const float* bhh_f = (const float*)d_in[6];
  const float* Wih_b = (const float*)d_in[7];
  const float* Whh_b = (const float*)d_in[8];
  const float* bih_b = (const float*)d_in[9];
  const float* bhh_b = (const float*)d_in[10];
  const float* qWih  = (const float*)d_in[11];
  const float* qWhh  = (const float*)d_in[12];
  const float* qbih  = (const float*)d_in[13];
  const float* qbhh  = (const float*)d_in[14];
  const float* Wr    = (const float*)d_in[15];
  const float* Ur    = (const float*)d_in[16];
  const float* br    = (const float*)d_in[17];
  const float* Wm    = (const float*)d_in[18];
  const float* Um    = (const float*)d_in[19];
  const float* z1_w  = (const float*)d_in[20];
  const float* z1_b  = (const float*)d_in[21];
  const float* z2_w  = (const float*)d_in[22];
  const float* z2_b  = (const float*)d_in[23];
  const float* nm_w  = (const float*)d_in[24];
  const float* nm_b  = (const float*)d_in[25];
  const float* ans_w = (const float*)d_in[26];
  const float* ans_b = (const float*)d_in[27];
  (void)in_sizes; (void)n_in; (void)out_size; (void)ws_size;

  float* ws = (float*)d_ws;
  float* WrT      = ws + 0;          // 262144
  float* UrT      = ws + 262144;     // 262144
  float* WT       = ws + 524288;     // 262144
  float* UT       = ws + 786432;     // 262144
  float* facts_in = ws + 1048576;    // 2097152  (reused as fRW)
  float* qe       = ws + 3145728;    // 1048576
  float* gx_f     = ws + 4194304;    // 6291456  (reused as zb16 in hops)
  float* gx_b     = ws + 10485760;   // 6291456
  float* gx_q     = ws + 16777216;   // 3145728  (reused as g1)
  float* facts    = ws + 19922944;   // 2097152
  float* hb       = ws + 22020096;   // 2097152  (reused as fW)
  // tagged exchange region:
  unsigned* Hg = (unsigned*)(ws + 24117248);   // 3 GRUs x 2 x 32768 = 196608 u32
  unsigned* Ct = (unsigned*)(ws + 24313856);   // 2 x 32768 = 65536 u32
  float* C0   = ws + 24379392;       // 32768 (final AGRU state, f32)
  float* qbuf = ws + 24412160;       // 32768 (question state, f32)
  float* M0   = ws + 24444928;       // 32768
  float* M1   = ws + 24477696;       // 32768
  float* Gm   = ws + 24510464;       // 4096
  ushort_t* zb16 = (ushort_t*)gx_f;  // 4096x2048 bf16
  float* g1  = gx_q;
  float* fRW = facts_in;
  float* fW  = hb;
  float* preds = (float*)d_out;
  float* q = qbuf;

  // ---- zero tagged-exchange buffers once per launch (in-graph) ----
  hipMemsetAsync(Hg, 0, (196608 + 65536) * sizeof(unsigned), stream);

  // ---- stage A: embeddings + weight transposes ----
  k_embed_facts<<<B * S, 256, 0, stream>>>(contexts, emb, facts_in);
  k_embed_q<<<B * TQ, 256, 0, stream>>>(questions, emb, qe);
  dim3 tb(32, 8);
  k_transpose512<<<dim3(16, 16), tb, 0, stream>>>(Wr, WrT);
  k_transpose512<<<dim3(16, 16), tb, 0, stream>>>(Ur, UrT);
  k_transpose512<<<dim3(16, 16), tb, 0, stream>>>(Wm, WT);
  k_transpose512<<<dim3(16, 16), tb, 0, stream>>>(Um, UT);

  // ---- stage B: input-side gate GEMMs (bf16 MFMA) ----
  k_gemm_mfma<false, 0><<<dim3(24, 64), 256, 0, stream>>>(facts_in, Wih_f, bih_f, gx_f, 4096, 1536, 512);
  k_gemm_mfma<false, 0><<<dim3(24, 64), 256, 0, stream>>>(facts_in, Wih_b, bih_b, gx_b, 4096, 1536, 512);
  k_gemm_mfma<false, 0><<<dim3(24, 32), 256, 0, stream>>>(qe, qWih, qbih, gx_q, 2048, 1536, 512);

  // ---- stage C: MFMA persistent GRU scans (plain launch, 96 WGs) ----
  k_gru_scan_mfma<<<96, 256, 0, stream>>>(Whh_f, bhh_f, Whh_b, bhh_b, qWhh, qbhh,
                                          gx_f, gx_b, gx_q, Hg, qbuf, facts, hb);
  k_add<<<2048, 256, 0, stream>>>(facts, hb);

  // ---- stage D: hop-invariant precomputes (bf16 MFMA) ----
  k_gemm_mfma<false, 0><<<dim3(8, 64), 256, 0, stream>>>(facts, WrT, nullptr, fRW, 4096, 512, 512);
  k_gemm_mfma<false, 0><<<dim3(8, 64), 256, 0, stream>>>(facts, WT,  nullptr, fW,  4096, 512, 512);

  // ---- stage E: episodic memory hops ----
  const float* Mcur = q;
  for (int h = 0; h < 3; ++h) {
    k_build_z16<<<B * S, 256, 0, stream>>>(facts, q, Mcur, zb16);
    k_gemm_mfma<true, 1><<<dim3(8, 64), 256, 0, stream>>>(zb16, z1_w, z1_b, g1, 4096, 512, 2048);
    k_score_softmax<<<B, 256, 0, stream>>>(g1, z2_w, z2_b, Gm);
    k_agru_scan_mfma<<<32, 256, 0, stream>>>(UrT, UT, fRW, fW, br, Gm, Ct, C0, h * 64);
    float* Mnext = (h & 1) ? M1 : M0;
    k_gemm_cat3<<<dim3(8, 1), 256, 0, stream>>>(Mcur, C0, q, nm_w, nm_b, Mnext);
    Mcur = Mnext;
  }

  // ---- stage F: answer projection (fused concat2) ----
  k_gemm_cat2<<<dim3(500, 1), 256, 0, stream>>>(Mcur, q, ans_w, ans_b, preds);
}

// Round 13
// 1361.910 us; speedup vs baseline: 1.1191x; 1.1191x over previous
//
#include <hip/hip_runtime.h>
#include <cstddef>
#include <cstdint>

namespace {

constexpr int H  = 512;
constexpr int V  = 32000;
constexpr int B  = 64;
constexpr int S  = 64;
constexpr int T  = 32;
constexpr int TQ = 32;

typedef unsigned short ushort_t;
typedef __attribute__((ext_vector_type(8))) short bf16x8;
typedef __attribute__((ext_vector_type(4))) short bf16x4;
typedef __attribute__((ext_vector_type(4))) float f32x4;
typedef __attribute__((ext_vector_type(4))) unsigned u32x4;

__device__ __forceinline__ ushort_t f2bf(float f) {
  union { float f; unsigned u; } v; v.f = f;
  return (ushort_t)((v.u + 0x7FFFu + ((v.u >> 16) & 1u)) >> 16);
}

__device__ __forceinline__ float sigm(float x) { return 1.f / (1.f + expf(-x)); }

__device__ __forceinline__ bf16x8 pack8(f32x4 a, f32x4 b) {
  bf16x8 r;
  r[0] = (short)f2bf(a[0]); r[1] = (short)f2bf(a[1]);
  r[2] = (short)f2bf(a[2]); r[3] = (short)f2bf(a[3]);
  r[4] = (short)f2bf(b[0]); r[5] = (short)f2bf(b[1]);
  r[6] = (short)f2bf(b[2]); r[7] = (short)f2bf(b[3]);
  return r;
}

// ---- cross-XCD coherent data movement: sc0 sc1 ONLY (rounds 5-10 proven;
// round-11 erratum: sc0-only polling deadlocks; round-12 erratum: polling
// the data directly floods the coherence point) -----------------------------
__device__ __forceinline__ u32x4 ld16c(const void* p) {
  u32x4 v;
  asm volatile("global_load_dwordx4 %0, %1, off sc0 sc1" : "=v"(v) : "v"(p));
  return v;
}
__device__ __forceinline__ void st2c(ushort_t* p, unsigned v) {
  asm volatile("global_store_short %0, %1, off sc0 sc1" :: "v"(p), "v"(v) : "memory");
}
__device__ __forceinline__ void stflag(unsigned* p, unsigned v) {
  asm volatile("global_store_dword %0, %1, off sc0 sc1" :: "v"(p), "v"(v) : "memory");
}
__device__ __forceinline__ unsigned ldflag(const unsigned* p) {
  unsigned v;
  asm volatile("global_load_dword %0, %1, off sc0 sc1" : "=v"(v) : "v"(p));
  return v;
}
__device__ __forceinline__ void waitvm0() {
  asm volatile("s_waitcnt vmcnt(0)" ::: "memory");
  __builtin_amdgcn_sched_barrier(0);
}

// ---------------------------------------------------------------------------
// Embedding + positional encoding
// ---------------------------------------------------------------------------
__global__ __launch_bounds__(256) void k_embed_facts(const int* __restrict__ ctx,
                                                     const float* __restrict__ emb,
                                                     float* __restrict__ facts_in) {
  const int bs = blockIdx.x;
  const int s  = bs & (S - 1);
  const int t  = threadIdx.x;
  __shared__ int sidx[T];
  if (t < T) sidx[t] = ctx[(size_t)bs * T + t];
  __syncthreads();
  float a0 = 0.f, a1 = 0.f;
  for (int tt = 0; tt < T; ++tt) {
    const int ix = sidx[tt];
    if (ix != 0) {
      const float* e = emb + ((size_t)ix << 9);
      a0 += e[t];
      a1 += e[t + 256];
    }
  }
  const float sf = (float)s * (1.f / 64.f);
  const float c1 = 1.f - sf;
  const float c2 = (1.f - 2.f * sf) * (1.f / 512.f);
  facts_in[((size_t)bs << 9) + t]       = a0 * (c1 - (float)t * c2);
  facts_in[((size_t)bs << 9) + t + 256] = a1 * (c1 - (float)(t + 256) * c2);
}

__global__ __launch_bounds__(256) void k_embed_q(const int* __restrict__ qidx,
                                                 const float* __restrict__ emb,
                                                 float* __restrict__ qe) {
  const int bt = blockIdx.x;
  const int t  = threadIdx.x;
  const int ix = qidx[bt];
  float v0 = 0.f, v1 = 0.f;
  if (ix != 0) {
    const float* e = emb + ((size_t)ix << 9);
    v0 = e[t];
    v1 = e[t + 256];
  }
  qe[((size_t)bt << 9) + t]       = v0;
  qe[((size_t)bt << 9) + t + 256] = v1;
}

__global__ __launch_bounds__(256) void k_transpose512(const float* __restrict__ src,
                                                      float* __restrict__ dst) {
  __shared__ float tile[32][33];
  const int x0 = blockIdx.x * 32, y0 = blockIdx.y * 32;
  for (int i = threadIdx.y; i < 32; i += 8)
    tile[i][threadIdx.x] = src[(size_t)(y0 + i) * H + x0 + threadIdx.x];
  __syncthreads();
  for (int i = threadIdx.y; i < 32; i += 8)
    dst[(size_t)(x0 + i) * H + y0 + threadIdx.x] = tile[threadIdx.x][i];
}

// ---------------------------------------------------------------------------
// bf16 MFMA GEMM (NT), round-2/8 proven. A: bf16 (A_BF16) or f32.
// ---------------------------------------------------------------------------
template <bool A_BF16, int ACT>
__global__ __launch_bounds__(256) void k_gemm_mfma(const void* __restrict__ Av,
                                                   const float* __restrict__ Bm,
                                                   const float* __restrict__ bias,
                                                   float* __restrict__ C,
                                                   int M, int N, int K) {
  __shared__ __align__(16) ushort_t As[64][72];
  __shared__ __align__(16) ushort_t Bs[64][72];
  const int t    = threadIdx.x;
  const int lane = t & 63;
  const int w    = t >> 6;
  const int wr   = w >> 1, wc = w & 1;
  const int m0 = blockIdx.y << 6, n0 = blockIdx.x << 6;
  const int row = t >> 2;
  const int ch  = t & 3;

  f32x4 acc[2][2] = {};

  for (int k0 = 0; k0 < K; k0 += 64) {
    if (A_BF16) {
      const ushort_t* A16 = (const ushort_t*)Av;
#pragma unroll
      for (int cc = 0; cc < 2; ++cc) {
        const int c8 = ch + cc * 4;
        const uint4 v = *(const uint4*)(A16 + (size_t)(m0 + row) * K + k0 + c8 * 8);
        *(uint4*)&As[row][c8 * 8] = v;
      }
    } else {
      const float* Af = (const float*)Av;
#pragma unroll
      for (int cc = 0; cc < 2; ++cc) {
        const int c8 = ch + cc * 4;
        const float* src = Af + (size_t)(m0 + row) * K + k0 + c8 * 8;
        *(bf16x8*)&As[row][c8 * 8] = pack8(*(const f32x4*)src, *(const f32x4*)(src + 4));
      }
    }
#pragma unroll
    for (int cc = 0; cc < 2; ++cc) {
      const int c8 = ch + cc * 4;
      const float* srb = Bm + (size_t)(n0 + row) * K + k0 + c8 * 8;
      *(bf16x8*)&Bs[row][c8 * 8] = pack8(*(const f32x4*)srb, *(const f32x4*)(srb + 4));
    }
    __syncthreads();
#pragma unroll
    for (int ks = 0; ks < 2; ++ks) {
      bf16x8 a[2], b[2];
#pragma unroll
      for (int fr = 0; fr < 2; ++fr)
        a[fr] = *(const bf16x8*)&As[wr * 32 + fr * 16 + (lane & 15)][ks * 32 + (lane >> 4) * 8];
#pragma unroll
      for (int fc = 0; fc < 2; ++fc)
        b[fc] = *(const bf16x8*)&Bs[wc * 32 + fc * 16 + (lane & 15)][ks * 32 + (lane >> 4) * 8];
#pragma unroll
      for (int fr = 0; fr < 2; ++fr)
#pragma unroll
        for (int fc = 0; fc < 2; ++fc)
          acc[fr][fc] = __builtin_amdgcn_mfma_f32_16x16x32_bf16(a[fr], b[fc], acc[fr][fc], 0, 0, 0);
    }
    __syncthreads();
  }
#pragma unroll
  for (int fr = 0; fr < 2; ++fr) {
#pragma unroll
    for (int fc = 0; fc < 2; ++fc) {
      const int rbase = m0 + wr * 32 + fr * 16 + ((lane >> 4) << 2);
      const int col   = n0 + wc * 32 + fc * 16 + (lane & 15);
      const float bv  = bias ? bias[col] : 0.f;
#pragma unroll
      for (int j = 0; j < 4; ++j) {
        float v = acc[fr][fc][j] + bv;
        if (ACT == 1) v = tanhf(v);
        if (ACT == 2) v = fmaxf(v, 0.f);
        C[(size_t)(rbase + j) * N + col] = v;
      }
    }
  }
}

// z (bf16) = [f*q, f*M, |f-q|, |f-M|]
__global__ __launch_bounds__(256) void k_build_z16(const float* __restrict__ facts,
                                                   const float* __restrict__ q,
                                                   const float* __restrict__ M,
                                                   ushort_t* __restrict__ z) {
  const int bs = blockIdx.x;
  const int b  = bs >> 6;
  const int t  = threadIdx.x;
  const size_t zb = (size_t)bs << 11;
  for (int c = t; c < 512; c += 256) {
    const float f  = facts[((size_t)bs << 9) + c];
    const float qv = q[(b << 9) + c];
    const float mv = M[(b << 9) + c];
    z[zb + c]        = f2bf(f * qv);
    z[zb + 512 + c]  = f2bf(f * mv);
    z[zb + 1024 + c] = f2bf(fabsf(f - qv));
    z[zb + 1536 + c] = f2bf(fabsf(f - mv));
  }
}

// ---------------------------------------------------------------------------
// nm GEMM with fused concat3: A[64][1536] = [M | C | q]. relu.
// ---------------------------------------------------------------------------
__global__ __launch_bounds__(256) void k_gemm_cat3(const float* __restrict__ Mv,
                                                   const float* __restrict__ Cv,
                                                   const float* __restrict__ qv,
                                                   const float* __restrict__ Bm,
                                                   const float* __restrict__ bias,
                                                   float* __restrict__ C) {
  constexpr int N = 512, K = 1536;
  __shared__ __align__(16) ushort_t As[64][72];
  __shared__ __align__(16) ushort_t Bs[64][72];
  const int t    = threadIdx.x;
  const int lane = t & 63;
  const int w    = t >> 6;
  const int wr   = w >> 1, wc = w & 1;
  const int n0 = blockIdx.x << 6;
  const int row = t >> 2;
  const int ch  = t & 3;

  f32x4 acc[2][2] = {};

  for (int k0 = 0; k0 < K; k0 += 64) {
    const int seg = k0 >> 9;
    const float* src = (seg == 0) ? Mv : (seg == 1) ? Cv : qv;
    const int kb = k0 & 511;
#pragma unroll
    for (int cc = 0; cc < 2; ++cc) {
      const int c8 = ch + cc * 4;
      const float* fp = src + ((size_t)row << 9) + kb + c8 * 8;
      *(bf16x8*)&As[row][c8 * 8] = pack8(*(const f32x4*)fp, *(const f32x4*)(fp + 4));
      const float* srb = Bm + (size_t)(n0 + row) * K + k0 + c8 * 8;
      *(bf16x8*)&Bs[row][c8 * 8] = pack8(*(const f32x4*)srb, *(const f32x4*)(srb + 4));
    }
    __syncthreads();
#pragma unroll
    for (int ks = 0; ks < 2; ++ks) {
      bf16x8 a[2], bb[2];
#pragma unroll
      for (int fr = 0; fr < 2; ++fr)
        a[fr] = *(const bf16x8*)&As[wr * 32 + fr * 16 + (lane & 15)][ks * 32 + (lane >> 4) * 8];
#pragma unroll
      for (int fc = 0; fc < 2; ++fc)
        bb[fc] = *(const bf16x8*)&Bs[wc * 32 + fc * 16 + (lane & 15)][ks * 32 + (lane >> 4) * 8];
#pragma unroll
      for (int fr = 0; fr < 2; ++fr)
#pragma unroll
        for (int fc = 0; fc < 2; ++fc)
          acc[fr][fc] = __builtin_amdgcn_mfma_f32_16x16x32_bf16(a[fr], bb[fc], acc[fr][fc], 0, 0, 0);
    }
    __syncthreads();
  }
#pragma unroll
  for (int fr = 0; fr < 2; ++fr) {
#pragma unroll
    for (int fc = 0; fc < 2; ++fc) {
      const int rbase = wr * 32 + fr * 16 + ((lane >> 4) << 2);
      const int col   = n0 + wc * 32 + fc * 16 + (lane & 15);
      const float bv  = bias[col];
#pragma unroll
      for (int j = 0; j < 4; ++j)
        C[(size_t)(rbase + j) * N + col] = fmaxf(acc[fr][fc][j] + bv, 0.f);
    }
  }
}

// ---------------------------------------------------------------------------
// answer GEMM with fused concat2: A[64][1024] = [M | q]. N=32000.
// ---------------------------------------------------------------------------
__global__ __launch_bounds__(256) void k_gemm_cat2(const float* __restrict__ Mv,
                                                   const float* __restrict__ qv,
                                                   const float* __restrict__ Bm,
                                                   const float* __restrict__ bias,
                                                   float* __restrict__ C) {
  constexpr int N = 32000, K = 1024;
  __shared__ __align__(16) ushort_t As[64][72];
  __shared__ __align__(16) ushort_t Bs[64][72];
  const int t    = threadIdx.x;
  const int lane = t & 63;
  const int w    = t >> 6;
  const int wr   = w >> 1, wc = w & 1;
  const int n0 = blockIdx.x << 6;
  const int row = t >> 2;
  const int ch  = t & 3;

  f32x4 acc[2][2] = {};

  for (int k0 = 0; k0 < K; k0 += 64) {
    const float* src = (k0 < 512) ? Mv : qv;
    const int kb = k0 & 511;
#pragma unroll
    for (int cc = 0; cc < 2; ++cc) {
      const int c8 = ch + cc * 4;
      const float* fp = src + ((size_t)row << 9) + kb + c8 * 8;
      *(bf16x8*)&As[row][c8 * 8] = pack8(*(const f32x4*)fp, *(const f32x4*)(fp + 4));
      const float* srb = Bm + (size_t)(n0 + row) * K + k0 + c8 * 8;
      *(bf16x8*)&Bs[row][c8 * 8] = pack8(*(const f32x4*)srb, *(const f32x4*)(srb + 4));
    }
    __syncthreads();
#pragma unroll
    for (int ks = 0; ks < 2; ++ks) {
      bf16x8 a[2], bb[2];
#pragma unroll
      for (int fr = 0; fr < 2; ++fr)
        a[fr] = *(const bf16x8*)&As[wr * 32 + fr * 16 + (lane & 15)][ks * 32 + (lane >> 4) * 8];
#pragma unroll
      for (int fc = 0; fc < 2; ++fc)
        bb[fc] = *(const bf16x8*)&Bs[wc * 32 + fc * 16 + (lane & 15)][ks * 32 + (lane >> 4) * 8];
#pragma unroll
      for (int fr = 0; fr < 2; ++fr)
#pragma unroll
        for (int fc = 0; fc < 2; ++fc)
          acc[fr][fc] = __builtin_amdgcn_mfma_f32_16x16x32_bf16(a[fr], bb[fc], acc[fr][fc], 0, 0, 0);
    }
    __syncthreads();
  }
#pragma unroll
  for (int fr = 0; fr < 2; ++fr) {
#pragma unroll
    for (int fc = 0; fc < 2; ++fc) {
      const int rbase = wr * 32 + fr * 16 + ((lane >> 4) << 2);
      const int col   = n0 + wc * 32 + fc * 16 + (lane & 15);
      const float bv  = bias[col];
#pragma unroll
      for (int j = 0; j < 4; ++j)
        C[(size_t)(rbase + j) * N + col] = acc[fr][fc][j] + bv;
    }
  }
}

// ---------------------------------------------------------------------------
// MFMA persistent GRU scan, round-13: round-10 structure + slim release.
// Only the 4 exchange stores sit before the vmcnt(0) drain; out_seq stores
// and gx prefetch are issued AFTER the flag store so their latency hides
// under the poll instead of extending the release.
// 96 WGs = 12 groups (3 gru x 4 ib of 16 items) x 8. Plain launch.
// ---------------------------------------------------------------------------
__global__ __launch_bounds__(256, 1) void k_gru_scan_mfma(
    const float* __restrict__ Whh_f, const float* __restrict__ bhh_f,
    const float* __restrict__ Whh_b, const float* __restrict__ bhh_b,
    const float* __restrict__ qWhh,  const float* __restrict__ qbhh,
    const float* __restrict__ gx_f, const float* __restrict__ gx_b,
    const float* __restrict__ gx_q,
    ushort_t* __restrict__ H16, float* __restrict__ qbuf,
    float* __restrict__ facts, float* __restrict__ hb_all,
    unsigned* __restrict__ flags_base) {
  const int bx   = blockIdx.x;     // 96
  const int grp  = bx >> 3;        // 0..11
  const int rank = bx & 7;
  const int gru  = grp >> 2;
  const int ib   = grp & 3;        // 16 items each

  const float* Whh; const float* bhh; const float* gx;
  float* out_seq; int seqlen, rev;
  if (gru == 0)      { Whh = Whh_f; bhh = bhh_f; gx = gx_f; out_seq = facts;   seqlen = S;  rev = 0; }
  else if (gru == 1) { Whh = Whh_b; bhh = bhh_b; gx = gx_b; out_seq = hb_all;  seqlen = S;  rev = 1; }
  else               { Whh = qWhh;  bhh = qbhh;  gx = gx_q; out_seq = nullptr; seqlen = TQ; rev = 0; }
  ushort_t* Hb0 = H16 + gru * 65536;   // [64][512] bf16 exchange, parity 0
  ushort_t* Hb1 = Hb0 + 32768;

  __shared__ __align__(16) ushort_t hl[16 * 520];

  const int t    = threadIdx.x;
  const int lane = t & 63;
  const int wv   = t >> 6;
  const int nt   = (rank << 2) + wv;   // 0..31
  const int lm   = lane & 15;
  const int lk   = lane >> 4;          // 0..3
  const int col  = (nt << 4) + lm;

  // pack weight B-fragments once
  bf16x8 wf[3][16];
#pragma unroll
  for (int g = 0; g < 3; ++g) {
    const float* wrow = Whh + ((size_t)(g * 512 + col) << 9) + (lk << 3);
#pragma unroll
    for (int ks = 0; ks < 16; ++ks) {
      const float* p = wrow + ks * 32;
      wf[g][ks] = pack8(*(const f32x4*)p, *(const f32x4*)(p + 4));
    }
  }
  const float bv0 = bhh[col], bv1 = bhh[512 + col], bv2 = bhh[1024 + col];
  unsigned* flags = flags_base + grp * 8 * 32;

  // initial gx load (step 0)
  float xr[4], xz[4], xn[4];
  {
    const int xidx = rev ? (seqlen - 1) : 0;
#pragma unroll
    for (int j = 0; j < 4; ++j) {
      const int b = (ib << 4) + (lk << 2) + j;
      const size_t gxrow = ((size_t)b * seqlen + xidx) * 1536;
      xr[j] = gx[gxrow + col];
      xz[j] = gx[gxrow + 512 + col];
      xn[j] = gx[gxrow + 1024 + col];
    }
  }

  float hp[4] = {0.f, 0.f, 0.f, 0.f};   // f32 carry, register-resident

  for (int s = 0; s < seqlen; ++s) {
    if (s == 0) {
      for (int i = t; i < 4160; i += 256) ((unsigned*)hl)[i] = 0u;
    } else {
      const ushort_t* Hp16 = (s & 1) ? Hb1 : Hb0;
      u32x4 v[4];
#pragma unroll
      for (int u = 0; u < 4; ++u) {
        const int i = (u << 8) + t;          // 0..1023, 8 ushorts each
        v[u] = ld16c(Hp16 + ((size_t)((ib << 4) + (i >> 6)) << 9) + ((i << 3) & 511));
      }
      waitvm0();
#pragma unroll
      for (int u = 0; u < 4; ++u) {
        const int i = (u << 8) + t;
        *(u32x4*)&hl[(i >> 6) * 520 + ((i << 3) & 511)] = v[u];
      }
    }
    __syncthreads();

    f32x4 acc0 = {}, acc1 = {}, acc2 = {};
#pragma unroll
    for (int ks = 0; ks < 16; ++ks) {
      const bf16x8 a = *(const bf16x8*)&hl[lm * 520 + (ks << 5) + (lk << 3)];
      acc0 = __builtin_amdgcn_mfma_f32_16x16x32_bf16(a, wf[0][ks], acc0, 0, 0, 0);
      acc1 = __builtin_amdgcn_mfma_f32_16x16x32_bf16(a, wf[1][ks], acc1, 0, 0, 0);
      acc2 = __builtin_amdgcn_mfma_f32_16x16x32_bf16(a, wf[2][ks], acc2, 0, 0, 0);
    }

    const int xidx = rev ? (seqlen - 1 - s) : s;
    ushort_t* Hn16 = (s & 1) ? Hb0 : Hb1;
    float hn4[4];
#pragma unroll
    for (int j = 0; j < 4; ++j) {
      const int b = (ib << 4) + (lk << 2) + j;
      const float r = sigm(xr[j] + acc0[j] + bv0);
      const float z = sigm(xz[j] + acc1[j] + bv1);
      const float n = tanhf(xn[j] + r * (acc2[j] + bv2));
      const float hnew = (1.f - z) * n + z * hp[j];
      hp[j] = hnew;
      hn4[j] = hnew;
      if (s + 1 < seqlen) st2c(Hn16 + ((size_t)b << 9) + col, (unsigned)f2bf(hnew));
    }

    if (s + 1 < seqlen) {
      // release: drain covers ONLY the 4 exchange stores
      waitvm0();
      __syncthreads();
      if (t == 0) stflag(flags + rank * 32, (unsigned)(s + 1));
      // deferred work — drains under the poll
#pragma unroll
      for (int j = 0; j < 4; ++j) {
        const int b = (ib << 4) + (lk << 2) + j;
        if (out_seq) out_seq[((size_t)(b * S + xidx) << 9) + col] = hn4[j];
      }
      const int xidx2 = rev ? (seqlen - 2 - s) : (s + 1);
      float nxr[4], nxz[4], nxn[4];
#pragma unroll
      for (int j = 0; j < 4; ++j) {
        const int b = (ib << 4) + (lk << 2) + j;
        const size_t gxrow = ((size_t)b * seqlen + xidx2) * 1536;
        nxr[j] = gx[gxrow + col];
        nxz[j] = gx[gxrow + 512 + col];
        nxn[j] = gx[gxrow + 1024 + col];
      }
      if (wv == 0) {
        const unsigned* fp = flags + (lane & 7) * 32;
        for (;;) {
          const unsigned v = ldflag(fp);
          asm volatile("s_waitcnt vmcnt(0)" ::: "memory");
          const int ok = (lane >= 8) || (v >= (unsigned)(s + 1));
          if (__all(ok)) break;
          __builtin_amdgcn_s_sleep(1);
        }
      }
      __syncthreads();
#pragma unroll
      for (int j = 0; j < 4; ++j) { xr[j] = nxr[j]; xz[j] = nxz[j]; xn[j] = nxn[j]; }
    } else {
#pragma unroll
      for (int j = 0; j < 4; ++j) {
        const int b = (ib << 4) + (lk << 2) + j;
        if (out_seq) out_seq[((size_t)(b * S + xidx) << 9) + col] = hn4[j];
        if (gru == 2) qbuf[((size_t)b << 9) + col] = hn4[j];
      }
    }
  }
}

// ---------------------------------------------------------------------------
// MFMA persistent AGRU scan, round-13: round-10 structure + slim release.
// 32 WGs = 4 groups x 8. Plain launch.
// ---------------------------------------------------------------------------
__global__ __launch_bounds__(256, 1) void k_agru_scan_mfma(
    const float* __restrict__ UrT, const float* __restrict__ UT,
    const float* __restrict__ fRW, const float* __restrict__ fW,
    const float* __restrict__ br, const float* __restrict__ G,
    ushort_t* __restrict__ C16, float* __restrict__ C0f,
    unsigned* __restrict__ flags_base) {
  const int bx   = blockIdx.x;     // 32
  const int grp  = bx >> 3;        // 0..3 (16 items each)
  const int rank = bx & 7;
  ushort_t* Cb0 = C16;
  ushort_t* Cb1 = C16 + 32768;

  __shared__ __align__(16) ushort_t cl[16 * 520];

  const int t    = threadIdx.x;
  const int lane = t & 63;
  const int wv   = t >> 6;
  const int nt   = (rank << 2) + wv;
  const int lm   = lane & 15;
  const int lk   = lane >> 4;
  const int col  = (nt << 4) + lm;

  bf16x8 wfr[16], wfu[16];
  {
    const float* r0 = UrT + ((size_t)col << 9) + (lk << 3);
    const float* r1 = UT  + ((size_t)col << 9) + (lk << 3);
#pragma unroll
    for (int ks = 0; ks < 16; ++ks) {
      wfr[ks] = pack8(*(const f32x4*)(r0 + ks * 32), *(const f32x4*)(r0 + ks * 32 + 4));
      wfu[ks] = pack8(*(const f32x4*)(r1 + ks * 32), *(const f32x4*)(r1 + ks * 32 + 4));
    }
  }
  const float brv = br[col];
  unsigned* flags = flags_base + grp * 8 * 32;

  float fr[4], fw[4], gg[4];
#pragma unroll
  for (int j = 0; j < 4; ++j) {
    const int b = (grp << 4) + (lk << 2) + j;
    const size_t fi = ((size_t)(b * S) << 9) + col;
    fr[j] = fRW[fi];
    fw[j] = fW[fi];
    gg[j] = G[b << 6];
  }

  float cp[4] = {0.f, 0.f, 0.f, 0.f};

  for (int s = 0; s < S; ++s) {
    if (s == 0) {
      for (int i = t; i < 4160; i += 256) ((unsigned*)cl)[i] = 0u;
    } else {
      const ushort_t* Cp16 = (s & 1) ? Cb1 : Cb0;
      u32x4 v[4];
#pragma unroll
      for (int u = 0; u < 4; ++u) {
        const int i = (u << 8) + t;
        v[u] = ld16c(Cp16 + ((size_t)((grp << 4) + (i >> 6)) << 9) + ((i << 3) & 511));
      }
      waitvm0();
#pragma unroll
      for (int u = 0; u < 4; ++u) {
        const int i = (u << 8) + t;
        *(u32x4*)&cl[(i >> 6) * 520 + ((i << 3) & 511)] = v[u];
      }
    }
    __syncthreads();

    f32x4 accr = {}, accu = {};
#pragma unroll
    for (int ks = 0; ks < 16; ++ks) {
      const bf16x8 a = *(const bf16x8*)&cl[lm * 520 + (ks << 5) + (lk << 3)];
      accr = __builtin_amdgcn_mfma_f32_16x16x32_bf16(a, wfr[ks], accr, 0, 0, 0);
      accu = __builtin_amdgcn_mfma_f32_16x16x32_bf16(a, wfu[ks], accu, 0, 0, 0);
    }

    ushort_t* Cn16 = (s & 1) ? Cb0 : Cb1;
    float cn4[4];
#pragma unroll
    for (int j = 0; j < 4; ++j) {
      const int b = (grp << 4) + (lk << 2) + j;
      const float r  = sigm(fr[j] + accr[j] + brv);
      const float ht = tanhf(fw[j] + r * accu[j] + brv);
      const float cnew = gg[j] * ht + (1.f - gg[j]) * cp[j];
      cp[j] = cnew;
      cn4[j] = cnew;
      if (s + 1 < S) st2c(Cn16 + ((size_t)b << 9) + col, (unsigned)f2bf(cnew));
    }

    if (s + 1 < S) {
      waitvm0();
      __syncthreads();
      if (t == 0) stflag(flags + rank * 32, (unsigned)(s + 1));
      float nfr[4], nfw[4], ngg[4];
#pragma unroll
      for (int j = 0; j < 4; ++j) {
        const int b = (grp << 4) + (lk << 2) + j;
        const size_t fi = ((size_t)(b * S + s + 1) << 9) + col;
        nfr[j] = fRW[fi];
        nfw[j] = fW[fi];
        ngg[j] = G[(b << 6) + s + 1];
      }
      if (wv == 0) {
        const unsigned* fp = flags + (lane & 7) * 32;
        for (;;) {
          const unsigned v = ldflag(fp);
          asm volatile("s_waitcnt vmcnt(0)" ::: "memory");
          const int ok = (lane >= 8) || (v >= (unsigned)(s + 1));
          if (__all(ok)) break;
          __builtin_amdgcn_s_sleep(1);
        }
      }
      __syncthreads();
#pragma unroll
      for (int j = 0; j < 4; ++j) { fr[j] = nfr[j]; fw[j] = nfw[j]; gg[j] = ngg[j]; }
    } else {
#pragma unroll
      for (int j = 0; j < 4; ++j) {
        const int b = (grp << 4) + (lk << 2) + j;
        C0f[((size_t)b << 9) + col] = cn4[j];
      }
    }
  }
}

__global__ __launch_bounds__(256) void k_add(float* __restrict__ a, const float* __restrict__ b) {
  const size_t i = (((size_t)blockIdx.x << 8) + threadIdx.x) << 2;
  float4 x = *(float4*)(a + i);
  const float4 y = *(const float4*)(b + i);
  x.x += y.x; x.y += y.y; x.z += y.z; x.w += y.w;
  *(float4*)(a + i) = x;
}

__global__ __launch_bounds__(256) void k_score_softmax(const float* __restrict__ g1,
                                                       const float* __restrict__ z2w,
                                                       const float* __restrict__ z2b,
                                                       float* __restrict__ G) {
  const int b = blockIdx.x, t = threadIdx.x;
  const int wave = t >> 6, lane = t & 63;
  __shared__ float sc[64];
  for (int si = 0; si < 16; ++si) {
    const int s = wave * 16 + si;
    const float* row = g1 + ((size_t)(b * S + s) << 9) + lane * 8;
    const float* w   = z2w + lane * 8;
    float p = 0.f;
#pragma unroll
    for (int k = 0; k < 8; ++k) p += row[k] * w[k];
#pragma unroll
    for (int off = 32; off; off >>= 1) p += __shfl_xor(p, off);
    if (lane == 0) sc[s] = p + z2b[0];
  }
  __syncthreads();
  if (wave == 0) {
    const float v = sc[lane];
    float m = v;
#pragma unroll
    for (int off = 32; off; off >>= 1) m = fmaxf(m, __shfl_xor(m, off));
    const float e = expf(v - m);
    float su = e;
#pragma unroll
    for (int off = 32; off; off >>= 1) su += __shfl_xor(su, off);
    G[(b << 6) + lane] = e / su;
  }
}

}  // namespace

extern "C" void kernel_launch(void* const* d_in, const int* in_sizes, int n_in,
                              void* d_out, int out_size, void* d_ws, size_t ws_size,
                              hipStream_t stream) {
  const int*   contexts  = (const int*)d_in[0];
  const int*   questions = (const int*)d_in[1];
  const float* emb   = (const float*)d_in[2];
  const float* Wih_f = (const float*)d_in[3];
  const float* Whh_f = (const float*)d_in[4];
  const float* bih_f = (const float*)d_in[5];
  const float* bhh_f = (const float*)d_in[6];
  const float* Wih_b = (const float*)d_in[7];
  const float* Whh_b = (const float*)d_in[8];
  const float* bih_b = (const float*)d_in[9];
  const float* bhh_b = (const float*)d_in[10];
  const float* qWih  = (const float*)d_in[11];
  const float* qWhh  = (const float*)d_in[12];
  const float* qbih  = (const float*)d_in[13];
  const float* qbhh  = (const float*)d_in[14];
  const float* Wr    = (const float*)d_in[15];
  const float* Ur    = (const float*)d_in[16];
  const float* br    = (const float*)d_in[17];
  const float* Wm    = (const float*)d_in[18];
  const float* Um    = (const float*)d_in[19];
  const float* z1_w  = (const float*)d_in[20];
  const float* z1_b  = (const float*)d_in[21];
  const float* z2_w  = (const float*)d_in[22];
  const float* z2_b  = (const float*)d_in[23];
  const float* nm_w  = (const float*)d_in[24];
  const float* nm_b  = (const float*)d_in[25];
  const float* ans_w = (const float*)d_in[26];
  const float* ans_b = (const float*)d_in[27];
  (void)in_sizes; (void)n_in; (void)out_size; (void)ws_size;

  float* ws = (float*)d_ws;
  float* WrT      = ws + 0;          // 262144
  float* UrT      = ws + 262144;     // 262144
  float* WT       = ws + 524288;     // 262144
  float* UT       = ws + 786432;     // 262144
  float* facts_in = ws + 1048576;    // 2097152  (reused as fRW)
  float* qe       = ws + 3145728;    // 1048576
  float* gx_f     = ws + 4194304;    // 6291456  (reused as zb16 in hops)
  float* gx_b     = ws + 10485760;   // 6291456
  float* gx_q     = ws + 16777216;   // 3145728  (reused as g1)
  float* facts    = ws + 19922944;   // 2097152
  float* hb       = ws + 22020096;   // 2097152  (reused as fW)
  float* Hbuf     = ws + 24117248;   // 196608 floats: H16/q/C16 live here
  float* C0       = ws + 24313856;   // 32768 (final AGRU state, f32)
  float* M0       = ws + 24379392;   // 32768
  float* M1       = ws + 24412160;   // 32768
  float* Mq       = ws + 24543232;   // flags region
  float* Gm       = ws + 24608768;   // 4096
  ushort_t* H16 = (ushort_t*)Hbuf;             // 3 GRUs x 2 x [64][512] bf16
  float* qbuf   = Hbuf + 98304;                // 32768 floats (question state)
  ushort_t* C16 = (ushort_t*)(Hbuf + 131072);  // 2 x [64][512] bf16
  ushort_t* zb16 = (ushort_t*)gx_f;            // 4096x2048 bf16
  float* g1  = gx_q;
  float* fRW = facts_in;
  float* fW  = hb;
  float* preds = (float*)d_out;
  unsigned* bar = (unsigned*)Mq;     // flags: GRU 12*256 + 3 hops * 4*256 = 6144 u32
  float* q = qbuf;

  // ---- flags: zero once per call (monotone counters) ----
  hipMemsetAsync(bar, 0, 6144 * sizeof(unsigned), stream);

  // ---- stage A: embeddings + weight transposes ----
  k_embed_facts<<<B * S, 256, 0, stream>>>(contexts, emb, facts_in);
  k_embed_q<<<B * TQ, 256, 0, stream>>>(questions, emb, qe);
  dim3 tb(32, 8);
  k_transpose512<<<dim3(16, 16), tb, 0, stream>>>(Wr, WrT);
  k_transpose512<<<dim3(16, 16), tb, 0, stream>>>(Ur, UrT);
  k_transpose512<<<dim3(16, 16), tb, 0, stream>>>(Wm, WT);
  k_transpose512<<<dim3(16, 16), tb, 0, stream>>>(Um, UT);

  // ---- stage B: input-side gate GEMMs (bf16 MFMA) ----
  k_gemm_mfma<false, 0><<<dim3(24, 64), 256, 0, stream>>>(facts_in, Wih_f, bih_f, gx_f, 4096, 1536, 512);
  k_gemm_mfma<false, 0><<<dim3(24, 64), 256, 0, stream>>>(facts_in, Wih_b, bih_b, gx_b, 4096, 1536, 512);
  k_gemm_mfma<false, 0><<<dim3(24, 32), 256, 0, stream>>>(qe, qWih, qbih, gx_q, 2048, 1536, 512);

  // ---- stage C: MFMA persistent GRU scans (plain launch, 96 WGs) ----
  k_gru_scan_mfma<<<96, 256, 0, stream>>>(Whh_f, bhh_f, Whh_b, bhh_b, qWhh, qbhh,
                                          gx_f, gx_b, gx_q, H16, qbuf, facts, hb, bar);
  k_add<<<2048, 256, 0, stream>>>(facts, hb);

  // ---- stage D: hop-invariant precomputes (bf16 MFMA) ----
  k_gemm_mfma<false, 0><<<dim3(8, 64), 256, 0, stream>>>(facts, WrT, nullptr, fRW, 4096, 512, 512);
  k_gemm_mfma<false, 0><<<dim3(8, 64), 256, 0, stream>>>(facts, WT,  nullptr, fW,  4096, 512, 512);

  // ---- stage E: episodic memory hops ----
  const float* Mcur = q;
  for (int h = 0; h < 3; ++h) {
    k_build_z16<<<B * S, 256, 0, stream>>>(facts, q, Mcur, zb16);
    k_gemm_mfma<true, 1><<<dim3(8, 64), 256, 0, stream>>>(zb16, z1_w, z1_b, g1, 4096, 512, 2048);
    k_score_softmax<<<B, 256, 0, stream>>>(g1, z2_w, z2_b, Gm);
    unsigned* fl = bar + 3072 + h * 1024;
    k_agru_scan_mfma<<<32, 256, 0, stream>>>(UrT, UT, fRW, fW, br, Gm, C16, C0, fl);
    float* Mnext = (h & 1) ? M1 : M0;
    k_gemm_cat3<<<dim3(8, 1), 256, 0, stream>>>(Mcur, C0, q, nm_w, nm_b, Mnext);
    Mcur = Mnext;
  }

  // ---- stage F: answer projection (fused concat2) ----
  k_gemm_cat2<<<dim3(500, 1), 256, 0, stream>>>(Mcur, q, ans_w, ans_b, preds);
}

// Round 15
// 1330.318 us; speedup vs baseline: 1.1457x; 1.0237x over previous
//
#include <hip/hip_runtime.h>
#include <cstddef>
#include <cstdint>

namespace {

constexpr int H  = 512;
constexpr int V  = 32000;
constexpr int B  = 64;
constexpr int S  = 64;
constexpr int T  = 32;
constexpr int TQ = 32;

typedef unsigned short ushort_t;
typedef __attribute__((ext_vector_type(8))) short bf16x8;
typedef __attribute__((ext_vector_type(4))) short bf16x4;
typedef __attribute__((ext_vector_type(4))) float f32x4;
typedef __attribute__((ext_vector_type(4))) unsigned u32x4;

__device__ __forceinline__ ushort_t f2bf(float f) {
  union { float f; unsigned u; } v; v.f = f;
  return (ushort_t)((v.u + 0x7FFFu + ((v.u >> 16) & 1u)) >> 16);
}

__device__ __forceinline__ float sigm(float x) { return 1.f / (1.f + expf(-x)); }

__device__ __forceinline__ bf16x8 pack8(f32x4 a, f32x4 b) {
  bf16x8 r;
  r[0] = (short)f2bf(a[0]); r[1] = (short)f2bf(a[1]);
  r[2] = (short)f2bf(a[2]); r[3] = (short)f2bf(a[3]);
  r[4] = (short)f2bf(b[0]); r[5] = (short)f2bf(b[1]);
  r[6] = (short)f2bf(b[2]); r[7] = (short)f2bf(b[3]);
  return r;
}

// ---- cross-XCD coherent data movement: sc0 sc1 ONLY (rounds 5-13 proven) ---
__device__ __forceinline__ u32x4 ld16c(const void* p) {
  u32x4 v;
  asm volatile("global_load_dwordx4 %0, %1, off sc0 sc1" : "=v"(v) : "v"(p));
  return v;
}
__device__ __forceinline__ void st2c(ushort_t* p, unsigned v) {
  asm volatile("global_store_short %0, %1, off sc0 sc1" :: "v"(p), "v"(v) : "memory");
}
__device__ __forceinline__ void stflag(unsigned* p, unsigned v) {
  asm volatile("global_store_dword %0, %1, off sc0 sc1" :: "v"(p), "v"(v) : "memory");
}
__device__ __forceinline__ unsigned ldflag(const unsigned* p) {
  unsigned v;
  asm volatile("global_load_dword %0, %1, off sc0 sc1" : "=v"(v) : "v"(p));
  return v;
}
__device__ __forceinline__ void waitvm0() {
  asm volatile("s_waitcnt vmcnt(0)" ::: "memory");
  __builtin_amdgcn_sched_barrier(0);
}

// ---------------------------------------------------------------------------
// Embedding + positional encoding
// ---------------------------------------------------------------------------
__global__ __launch_bounds__(256) void k_embed_facts(const int* __restrict__ ctx,
                                                     const float* __restrict__ emb,
                                                     float* __restrict__ facts_in) {
  const int bs = blockIdx.x;
  const int s  = bs & (S - 1);
  const int t  = threadIdx.x;
  __shared__ int sidx[T];
  if (t < T) sidx[t] = ctx[(size_t)bs * T + t];
  __syncthreads();
  float a0 = 0.f, a1 = 0.f;
  for (int tt = 0; tt < T; ++tt) {
    const int ix = sidx[tt];
    if (ix != 0) {
      const float* e = emb + ((size_t)ix << 9);
      a0 += e[t];
      a1 += e[t + 256];
    }
  }
  const float sf = (float)s * (1.f / 64.f);
  const float c1 = 1.f - sf;
  const float c2 = (1.f - 2.f * sf) * (1.f / 512.f);
  facts_in[((size_t)bs << 9) + t]       = a0 * (c1 - (float)t * c2);
  facts_in[((size_t)bs << 9) + t + 256] = a1 * (c1 - (float)(t + 256) * c2);
}

__global__ __launch_bounds__(256) void k_embed_q(const int* __restrict__ qidx,
                                                 const float* __restrict__ emb,
                                                 float* __restrict__ qe) {
  const int bt = blockIdx.x;
  const int t  = threadIdx.x;
  const int ix = qidx[bt];
  float v0 = 0.f, v1 = 0.f;
  if (ix != 0) {
    const float* e = emb + ((size_t)ix << 9);
    v0 = e[t];
    v1 = e[t + 256];
  }
  qe[((size_t)bt << 9) + t]       = v0;
  qe[((size_t)bt << 9) + t + 256] = v1;
}

__global__ __launch_bounds__(256) void k_transpose512(const float* __restrict__ src,
                                                      float* __restrict__ dst) {
  __shared__ float tile[32][33];
  const int x0 = blockIdx.x * 32, y0 = blockIdx.y * 32;
  for (int i = threadIdx.y; i < 32; i += 8)
    tile[i][threadIdx.x] = src[(size_t)(y0 + i) * H + x0 + threadIdx.x];
  __syncthreads();
  for (int i = threadIdx.y; i < 32; i += 8)
    dst[(size_t)(x0 + i) * H + y0 + threadIdx.x] = tile[threadIdx.x][i];
}

// Bq/Bm repack: Bq = z1_w K-cols [0,512)u[1024,1536); Bm = [512,1024)u[1536,2048).
__global__ __launch_bounds__(256) void k_split_z1w(const float* __restrict__ z1w,
                                                   float* __restrict__ Bq,
                                                   float* __restrict__ Bm) {
  const int n = blockIdx.x;          // 0..511
  const int t = threadIdx.x;
  const float* src = z1w + (size_t)n * 2048;
  float* dq = Bq + (size_t)n * 1024;
  float* dm = Bm + (size_t)n * 1024;
  for (int k = t; k < 512; k += 256) {
    dq[k]       = src[k];
    dq[512 + k] = src[1024 + k];
    dm[k]       = src[512 + k];
    dm[512 + k] = src[1536 + k];
  }
}

// zq (bf16) = [f*q | |f-q|]  (hop-invariant half of z)
__global__ __launch_bounds__(256) void k_build_zq16(const float* __restrict__ facts,
                                                    const float* __restrict__ q,
                                                    ushort_t* __restrict__ zq) {
  const int bs = blockIdx.x;
  const int b  = bs >> 6;
  const int t  = threadIdx.x;
  const size_t zb = (size_t)bs << 10;
  for (int c = t; c < 512; c += 256) {
    const float f  = facts[((size_t)bs << 9) + c];
    const float qv = q[(b << 9) + c];
    zq[zb + c]       = f2bf(f * qv);
    zq[zb + 512 + c] = f2bf(fabsf(f - qv));
  }
}

// zm (bf16) = [f*M | |f-M|]  (per-hop half of z)
__global__ __launch_bounds__(256) void k_build_zm16(const float* __restrict__ facts,
                                                    const float* __restrict__ M,
                                                    ushort_t* __restrict__ zm) {
  const int bs = blockIdx.x;
  const int b  = bs >> 6;
  const int t  = threadIdx.x;
  const size_t zb = (size_t)bs << 10;
  for (int c = t; c < 512; c += 256) {
    const float f  = facts[((size_t)bs << 9) + c];
    const float mv = M[(b << 9) + c];
    zm[zb + c]       = f2bf(f * mv);
    zm[zb + 512 + c] = f2bf(fabsf(f - mv));
  }
}

// ---------------------------------------------------------------------------
// bf16 MFMA GEMM (NT), round-2/8 proven. A: bf16 (A_BF16) or f32.
// ADDC: epilogue adds Cin[m][n] (f32) before activation.
// ---------------------------------------------------------------------------
template <bool A_BF16, int ACT, bool ADDC>
__global__ __launch_bounds__(256) void k_gemm_mfma(const void* __restrict__ Av,
                                                   const float* __restrict__ Bm,
                                                   const float* __restrict__ bias,
                                                   float* __restrict__ C,
                                                   int M, int N, int K,
                                                   const float* __restrict__ Cin) {
  __shared__ __align__(16) ushort_t As[64][72];
  __shared__ __align__(16) ushort_t Bs[64][72];
  const int t    = threadIdx.x;
  const int lane = t & 63;
  const int w    = t >> 6;
  const int wr   = w >> 1, wc = w & 1;
  const int m0 = blockIdx.y << 6, n0 = blockIdx.x << 6;
  const int row = t >> 2;
  const int ch  = t & 3;

  f32x4 acc[2][2] = {};

  for (int k0 = 0; k0 < K; k0 += 64) {
    if (A_BF16) {
      const ushort_t* A16 = (const ushort_t*)Av;
#pragma unroll
      for (int cc = 0; cc < 2; ++cc) {
        const int c8 = ch + cc * 4;
        const uint4 v = *(const uint4*)(A16 + (size_t)(m0 + row) * K + k0 + c8 * 8);
        *(uint4*)&As[row][c8 * 8] = v;
      }
    } else {
      const float* Af = (const float*)Av;
#pragma unroll
      for (int cc = 0; cc < 2; ++cc) {
        const int c8 = ch + cc * 4;
        const float* src = Af + (size_t)(m0 + row) * K + k0 + c8 * 8;
        *(bf16x8*)&As[row][c8 * 8] = pack8(*(const f32x4*)src, *(const f32x4*)(src + 4));
      }
    }
#pragma unroll
    for (int cc = 0; cc < 2; ++cc) {
      const int c8 = ch + cc * 4;
      const float* srb = Bm + (size_t)(n0 + row) * K + k0 + c8 * 8;
      *(bf16x8*)&Bs[row][c8 * 8] = pack8(*(const f32x4*)srb, *(const f32x4*)(srb + 4));
    }
    __syncthreads();
#pragma unroll
    for (int ks = 0; ks < 2; ++ks) {
      bf16x8 a[2], b[2];
#pragma unroll
      for (int fr = 0; fr < 2; ++fr)
        a[fr] = *(const bf16x8*)&As[wr * 32 + fr * 16 + (lane & 15)][ks * 32 + (lane >> 4) * 8];
#pragma unroll
      for (int fc = 0; fc < 2; ++fc)
        b[fc] = *(const bf16x8*)&Bs[wc * 32 + fc * 16 + (lane & 15)][ks * 32 + (lane >> 4) * 8];
#pragma unroll
      for (int fr = 0; fr < 2; ++fr)
#pragma unroll
        for (int fc = 0; fc < 2; ++fc)
          acc[fr][fc] = __builtin_amdgcn_mfma_f32_16x16x32_bf16(a[fr], b[fc], acc[fr][fc], 0, 0, 0);
    }
    __syncthreads();
  }
#pragma unroll
  for (int fr = 0; fr < 2; ++fr) {
#pragma unroll
    for (int fc = 0; fc < 2; ++fc) {
      const int rbase = m0 + wr * 32 + fr * 16 + ((lane >> 4) << 2);
      const int col   = n0 + wc * 32 + fc * 16 + (lane & 15);
      const float bv  = bias ? bias[col] : 0.f;
#pragma unroll
      for (int j = 0; j < 4; ++j) {
        float v = acc[fr][fc][j] + bv;
        if (ADDC) v += Cin[(size_t)(rbase + j) * N + col];
        if (ACT == 1) v = tanhf(v);
        if (ACT == 2) v = fmaxf(v, 0.f);
        C[(size_t)(rbase + j) * N + col] = v;
      }
    }
  }
}

// ---------------------------------------------------------------------------
// Merged stage-B GEMM: grid.y ranges select {fwd, bwd, q} gate GEMMs.
// ---------------------------------------------------------------------------
__global__ __launch_bounds__(256) void k_gemm_b3(
    const float* __restrict__ facts_in, const float* __restrict__ qe,
    const float* __restrict__ Wih_f, const float* __restrict__ bih_f,
    const float* __restrict__ Wih_b, const float* __restrict__ bih_b,
    const float* __restrict__ qWih,  const float* __restrict__ qbih,
    float* __restrict__ gx_f, float* __restrict__ gx_b, float* __restrict__ gx_q) {
  constexpr int N = 1536, K = 512;
  const int y = blockIdx.y;
  const float* Af; const float* Bw; const float* bias; float* C; int m0;
  if (y < 64)       { Af = facts_in; Bw = Wih_f; bias = bih_f; C = gx_f; m0 = y << 6; }
  else if (y < 128) { Af = facts_in; Bw = Wih_b; bias = bih_b; C = gx_b; m0 = (y - 64) << 6; }
  else              { Af = qe;       Bw = qWih;  bias = qbih;  C = gx_q; m0 = (y - 128) << 6; }

  __shared__ __align__(16) ushort_t As[64][72];
  __shared__ __align__(16) ushort_t Bs[64][72];
  const int t    = threadIdx.x;
  const int lane = t & 63;
  const int w    = t >> 6;
  const int wr   = w >> 1, wc = w & 1;
  const int n0 = blockIdx.x << 6;
  const int row = t >> 2;
  const int ch  = t & 3;

  f32x4 acc[2][2] = {};

  for (int k0 = 0; k0 < K; k0 += 64) {
#pragma unroll
    for (int cc = 0; cc < 2; ++cc) {
      const int c8 = ch + cc * 4;
      const float* src = Af + (size_t)(m0 + row) * K + k0 + c8 * 8;
      *(bf16x8*)&As[row][c8 * 8] = pack8(*(const f32x4*)src, *(const f32x4*)(src + 4));
      const float* srb = Bw + (size_t)(n0 + row) * K + k0 + c8 * 8;
      *(bf16x8*)&Bs[row][c8 * 8] = pack8(*(const f32x4*)srb, *(const f32x4*)(srb + 4));
    }
    __syncthreads();
#pragma unroll
    for (int ks = 0; ks < 2; ++ks) {
      bf16x8 a[2], b[2];
#pragma unroll
      for (int fr = 0; fr < 2; ++fr)
        a[fr] = *(const bf16x8*)&As[wr * 32 + fr * 16 + (lane & 15)][ks * 32 + (lane >> 4) * 8];
#pragma unroll
      for (int fc = 0; fc < 2; ++fc)
        b[fc] = *(const bf16x8*)&Bs[wc * 32 + fc * 16 + (lane & 15)][ks * 32 + (lane >> 4) * 8];
#pragma unroll
      for (int fr = 0; fr < 2; ++fr)
#pragma unroll
        for (int fc = 0; fc < 2; ++fc)
          acc[fr][fc] = __builtin_amdgcn_mfma_f32_16x16x32_bf16(a[fr], b[fc], acc[fr][fc], 0, 0, 0);
    }
    __syncthreads();
  }
#pragma unroll
  for (int fr = 0; fr < 2; ++fr) {
#pragma unroll
    for (int fc = 0; fc < 2; ++fc) {
      const int rbase = m0 + wr * 32 + fr * 16 + ((lane >> 4) << 2);
      const int col   = n0 + wc * 32 + fc * 16 + (lane & 15);
      const float bv  = bias[col];
#pragma unroll
      for (int j = 0; j < 4; ++j)
        C[(size_t)(rbase + j) * N + col] = acc[fr][fc][j] + bv;
    }
  }
}

// ---------------------------------------------------------------------------
// Merged stage-D GEMM: y<64 -> facts@WrT->fRW ; else facts@WT->fW.
// ---------------------------------------------------------------------------
__global__ __launch_bounds__(256) void k_gemm_d2(
    const float* __restrict__ facts,
    const float* __restrict__ WrT, const float* __restrict__ WT,
    float* __restrict__ fRW, float* __restrict__ fW) {
  constexpr int N = 512, K = 512;
  const int y = blockIdx.y;
  const float* Bw = (y < 64) ? WrT : WT;
  float* C = (y < 64) ? fRW : fW;
  const int m0 = (y & 63) << 6;

  __shared__ __align__(16) ushort_t As[64][72];
  __shared__ __align__(16) ushort_t Bs[64][72];
  const int t    = threadIdx.x;
  const int lane = t & 63;
  const int w    = t >> 6;
  const int wr   = w >> 1, wc = w & 1;
  const int n0 = blockIdx.x << 6;
  const int row = t >> 2;
  const int ch  = t & 3;

  f32x4 acc[2][2] = {};

  for (int k0 = 0; k0 < K; k0 += 64) {
#pragma unroll
    for (int cc = 0; cc < 2; ++cc) {
      const int c8 = ch + cc * 4;
      const float* src = facts + (size_t)(m0 + row) * K + k0 + c8 * 8;
      *(bf16x8*)&As[row][c8 * 8] = pack8(*(const f32x4*)src, *(const f32x4*)(src + 4));
      const float* srb = Bw + (size_t)(n0 + row) * K + k0 + c8 * 8;
      *(bf16x8*)&Bs[row][c8 * 8] = pack8(*(const f32x4*)srb, *(const f32x4*)(srb + 4));
    }
    __syncthreads();
#pragma unroll
    for (int ks = 0; ks < 2; ++ks) {
      bf16x8 a[2], b[2];
#pragma unroll
      for (int fr = 0; fr < 2; ++fr)
        a[fr] = *(const bf16x8*)&As[wr * 32 + fr * 16 + (lane & 15)][ks * 32 + (lane >> 4) * 8];
#pragma unroll
      for (int fc = 0; fc < 2; ++fc)
        b[fc] = *(const bf16x8*)&Bs[wc * 32 + fc * 16 + (lane & 15)][ks * 32 + (lane >> 4) * 8];
#pragma unroll
      for (int fr = 0; fr < 2; ++fr)
#pragma unroll
        for (int fc = 0; fc < 2; ++fc)
          acc[fr][fc] = __builtin_amdgcn_mfma_f32_16x16x32_bf16(a[fr], b[fc], acc[fr][fc], 0, 0, 0);
    }
    __syncthreads();
  }
#pragma unroll
  for (int fr = 0; fr < 2; ++fr) {
#pragma unroll
    for (int fc = 0; fc < 2; ++fc) {
      const int rbase = m0 + wr * 32 + fr * 16 + ((lane >> 4) << 2);
      const int col   = n0 + wc * 32 + fc * 16 + (lane & 15);
#pragma unroll
      for (int j = 0; j < 4; ++j)
        C[(size_t)(rbase + j) * N + col] = acc[fr][fc][j];
    }
  }
}

// ---------------------------------------------------------------------------
// nm GEMM with fused concat3: A[64][1536] = [M | C | q]. relu.
// ---------------------------------------------------------------------------
__global__ __launch_bounds__(256) void k_gemm_cat3(const float* __restrict__ Mv,
                                                   const float* __restrict__ Cv,
                                                   const float* __restrict__ qv,
                                                   const float* __restrict__ Bm,
                                                   const float* __restrict__ bias,
                                                   float* __restrict__ C) {
  constexpr int N = 512, K = 1536;
  __shared__ __align__(16) ushort_t As[64][72];
  __shared__ __align__(16) ushort_t Bs[64][72];
  const int t    = threadIdx.x;
  const int lane = t & 63;
  const int w    = t >> 6;
  const int wr   = w >> 1, wc = w & 1;
  const int n0 = blockIdx.x << 6;
  const int row = t >> 2;
  const int ch  = t & 3;

  f32x4 acc[2][2] = {};

  for (int k0 = 0; k0 < K; k0 += 64) {
    const int seg = k0 >> 9;
    const float* src = (seg == 0) ? Mv : (seg == 1) ? Cv : qv;
    const int kb = k0 & 511;
#pragma unroll
    for (int cc = 0; cc < 2; ++cc) {
      const int c8 = ch + cc * 4;
      const float* fp = src + ((size_t)row << 9) + kb + c8 * 8;
      *(bf16x8*)&As[row][c8 * 8] = pack8(*(const f32x4*)fp, *(const f32x4*)(fp + 4));
      const float* srb = Bm + (size_t)(n0 + row) * K + k0 + c8 * 8;
      *(bf16x8*)&Bs[row][c8 * 8] = pack8(*(const f32x4*)srb, *(const f32x4*)(srb + 4));
    }
    __syncthreads();
#pragma unroll
    for (int ks = 0; ks < 2; ++ks) {
      bf16x8 a[2], bb[2];
#pragma unroll
      for (int fr = 0; fr < 2; ++fr)
        a[fr] = *(const bf16x8*)&As[wr * 32 + fr * 16 + (lane & 15)][ks * 32 + (lane >> 4) * 8];
#pragma unroll
      for (int fc = 0; fc < 2; ++fc)
        bb[fc] = *(const bf16x8*)&Bs[wc * 32 + fc * 16 + (lane & 15)][ks * 32 + (lane >> 4) * 8];
#pragma unroll
      for (int fr = 0; fr < 2; ++fr)
#pragma unroll
        for (int fc = 0; fc < 2; ++fc)
          acc[fr][fc] = __builtin_amdgcn_mfma_f32_16x16x32_bf16(a[fr], bb[fc], acc[fr][fc], 0, 0, 0);
    }
    __syncthreads();
  }
#pragma unroll
  for (int fr = 0; fr < 2; ++fr) {
#pragma unroll
    for (int fc = 0; fc < 2; ++fc) {
      const int rbase = wr * 32 + fr * 16 + ((lane >> 4) << 2);
      const int col   = n0 + wc * 32 + fc * 16 + (lane & 15);
      const float bv  = bias[col];
#pragma unroll
      for (int j = 0; j < 4; ++j)
        C[(size_t)(rbase + j) * N + col] = fmaxf(acc[fr][fc][j] + bv, 0.f);
    }
  }
}

// ---------------------------------------------------------------------------
// answer GEMM with fused concat2: A[64][1024] = [M | q]. N=32000.
// ---------------------------------------------------------------------------
__global__ __launch_bounds__(256) void k_gemm_cat2(const float* __restrict__ Mv,
                                                   const float* __restrict__ qv,
                                                   const float* __restrict__ Bm,
                                                   const float* __restrict__ bias,
                                                   float* __restrict__ C) {
  constexpr int N = 32000, K = 1024;
  __shared__ __align__(16) ushort_t As[64][72];
  __shared__ __align__(16) ushort_t Bs[64][72];
  const int t    = threadIdx.x;
  const int lane = t & 63;
  const int w    = t >> 6;
  const int wr   = w >> 1, wc = w & 1;
  const int n0 = blockIdx.x << 6;
  const int row = t >> 2;
  const int ch  = t & 3;

  f32x4 acc[2][2] = {};

  for (int k0 = 0; k0 < K; k0 += 64) {
    const float* src = (k0 < 512) ? Mv : qv;
    const int kb = k0 & 511;
#pragma unroll
    for (int cc = 0; cc < 2; ++cc) {
      const int c8 = ch + cc * 4;
      const float* fp = src + ((size_t)row << 9) + kb + c8 * 8;
      *(bf16x8*)&As[row][c8 * 8] = pack8(*(const f32x4*)fp, *(const f32x4*)(fp + 4));
      const float* srb = Bm + (size_t)(n0 + row) * K + k0 + c8 * 8;
      *(bf16x8*)&Bs[row][c8 * 8] = pack8(*(const f32x4*)srb, *(const f32x4*)(srb + 4));
    }
    __syncthreads();
#pragma unroll
    for (int ks = 0; ks < 2; ++ks) {
      bf16x8 a[2], bb[2];
#pragma unroll
      for (int fr = 0; fr < 2; ++fr)
        a[fr] = *(const bf16x8*)&As[wr * 32 + fr * 16 + (lane & 15)][ks * 32 + (lane >> 4) * 8];
#pragma unroll
      for (int fc = 0; fc < 2; ++fc)
        bb[fc] = *(const bf16x8*)&Bs[wc * 32 + fc * 16 + (lane & 15)][ks * 32 + (lane >> 4) * 8];
#pragma unroll
      for (int fr = 0; fr < 2; ++fr)
#pragma unroll
        for (int fc = 0; fc < 2; ++fc)
          acc[fr][fc] = __builtin_amdgcn_mfma_f32_16x16x32_bf16(a[fr], bb[fc], acc[fr][fc], 0, 0, 0);
    }
    __syncthreads();
  }
#pragma unroll
  for (int fr = 0; fr < 2; ++fr) {
#pragma unroll
    for (int fc = 0; fc < 2; ++fc) {
      const int rbase = wr * 32 + fr * 16 + ((lane >> 4) << 2);
      const int col   = n0 + wc * 32 + fc * 16 + (lane & 15);
      const float bv  = bias[col];
#pragma unroll
      for (int j = 0; j < 4; ++j)
        C[(size_t)(rbase + j) * N + col] = acc[fr][fc][j] + bv;
    }
  }
}

// ---------------------------------------------------------------------------
// MFMA persistent GRU scan (round-13 proven, unchanged).
// ---------------------------------------------------------------------------
__global__ __launch_bounds__(256, 1) void k_gru_scan_mfma(
    const float* __restrict__ Whh_f, const float* __restrict__ bhh_f,
    const float* __restrict__ Whh_b, const float* __restrict__ bhh_b,
    const float* __restrict__ qWhh,  const float* __restrict__ qbhh,
    const float* __restrict__ gx_f, const float* __restrict__ gx_b,
    const float* __restrict__ gx_q,
    ushort_t* __restrict__ H16, float* __restrict__ qbuf,
    float* __restrict__ facts, float* __restrict__ hb_all,
    unsigned* __restrict__ flags_base) {
  const int bx   = blockIdx.x;     // 96
  const int grp  = bx >> 3;        // 0..11
  const int rank = bx & 7;
  const int gru  = grp >> 2;
  const int ib   = grp & 3;        // 16 items each

  const float* Whh; const float* bhh; const float* gx;
  float* out_seq; int seqlen, rev;
  if (gru == 0)      { Whh = Whh_f; bhh = bhh_f; gx = gx_f; out_seq = facts;   seqlen = S;  rev = 0; }
  else if (gru == 1) { Whh = Whh_b; bhh = bhh_b; gx = gx_b; out_seq = hb_all;  seqlen = S;  rev = 1; }
  else               { Whh = qWhh;  bhh = qbhh;  gx = gx_q; out_seq = nullptr; seqlen = TQ; rev = 0; }
  ushort_t* Hb0 = H16 + gru * 65536;
  ushort_t* Hb1 = Hb0 + 32768;

  __shared__ __align__(16) ushort_t hl[16 * 520];

  const int t    = threadIdx.x;
  const int lane = t & 63;
  const int wv   = t >> 6;
  const int nt   = (rank << 2) + wv;   // 0..31
  const int lm   = lane & 15;
  const int lk   = lane >> 4;          // 0..3
  const int col  = (nt << 4) + lm;

  bf16x8 wf[3][16];
#pragma unroll
  for (int g = 0; g < 3; ++g) {
    const float* wrow = Whh + ((size_t)(g * 512 + col) << 9) + (lk << 3);
#pragma unroll
    for (int ks = 0; ks < 16; ++ks) {
      const float* p = wrow + ks * 32;
      wf[g][ks] = pack8(*(const f32x4*)p, *(const f32x4*)(p + 4));
    }
  }
  const float bv0 = bhh[col], bv1 = bhh[512 + col], bv2 = bhh[1024 + col];
  unsigned* flags = flags_base + grp * 8 * 32;

  float xr[4], xz[4], xn[4];
  {
    const int xidx = rev ? (seqlen - 1) : 0;
#pragma unroll
    for (int j = 0; j < 4; ++j) {
      const int b = (ib << 4) + (lk << 2) + j;
      const size_t gxrow = ((size_t)b * seqlen + xidx) * 1536;
      xr[j] = gx[gxrow + col];
      xz[j] = gx[gxrow + 512 + col];
      xn[j] = gx[gxrow + 1024 + col];
    }
  }

  float hp[4] = {0.f, 0.f, 0.f, 0.f};

  for (int s = 0; s < seqlen; ++s) {
    if (s == 0) {
      for (int i = t; i < 4160; i += 256) ((unsigned*)hl)[i] = 0u;
    } else {
      const ushort_t* Hp16 = (s & 1) ? Hb1 : Hb0;
      u32x4 v[4];
#pragma unroll
      for (int u = 0; u < 4; ++u) {
        const int i = (u << 8) + t;
        v[u] = ld16c(Hp16 + ((size_t)((ib << 4) + (i >> 6)) << 9) + ((i << 3) & 511));
      }
      waitvm0();
#pragma unroll
      for (int u = 0; u < 4; ++u) {
        const int i = (u << 8) + t;
        *(u32x4*)&hl[(i >> 6) * 520 + ((i << 3) & 511)] = v[u];
      }
    }
    __syncthreads();

    f32x4 acc0 = {}, acc1 = {}, acc2 = {};
#pragma unroll
    for (int ks = 0; ks < 16; ++ks) {
      const bf16x8 a = *(const bf16x8*)&hl[lm * 520 + (ks << 5) + (lk << 3)];
      acc0 = __builtin_amdgcn_mfma_f32_16x16x32_bf16(a, wf[0][ks], acc0, 0, 0, 0);
      acc1 = __builtin_amdgcn_mfma_f32_16x16x32_bf16(a, wf[1][ks], acc1, 0, 0, 0);
      acc2 = __builtin_amdgcn_mfma_f32_16x16x32_bf16(a, wf[2][ks], acc2, 0, 0, 0);
    }

    const int xidx = rev ? (seqlen - 1 - s) : s;
    ushort_t* Hn16 = (s & 1) ? Hb0 : Hb1;
    float hn4[4];
#pragma unroll
    for (int j = 0; j < 4; ++j) {
      const int b = (ib << 4) + (lk << 2) + j;
      const float r = sigm(xr[j] + acc0[j] + bv0);
      const float z = sigm(xz[j] + acc1[j] + bv1);
      const float n = tanhf(xn[j] + r * (acc2[j] + bv2));
      const float hnew = (1.f - z) * n + z * hp[j];
      hp[j] = hnew;
      hn4[j] = hnew;
      if (s + 1 < seqlen) st2c(Hn16 + ((size_t)b << 9) + col, (unsigned)f2bf(hnew));
    }

    if (s + 1 < seqlen) {
      waitvm0();
      __syncthreads();
      if (t == 0) stflag(flags + rank * 32, (unsigned)(s + 1));
#pragma unroll
      for (int j = 0; j < 4; ++j) {
        const int b = (ib << 4) + (lk << 2) + j;
        if (out_seq) out_seq[((size_t)(b * S + xidx) << 9) + col] = hn4[j];
      }
      const int xidx2 = rev ? (seqlen - 2 - s) : (s + 1);
      float nxr[4], nxz[4], nxn[4];
#pragma unroll
      for (int j = 0; j < 4; ++j) {
        const int b = (ib << 4) + (lk << 2) + j;
        const size_t gxrow = ((size_t)b * seqlen + xidx2) * 1536;
        nxr[j] = gx[gxrow + col];
        nxz[j] = gx[gxrow + 512 + col];
        nxn[j] = gx[gxrow + 1024 + col];
      }
      if (wv == 0) {
        const unsigned* fp = flags + (lane & 7) * 32;
        for (;;) {
          const unsigned v = ldflag(fp);
          asm volatile("s_waitcnt vmcnt(0)" ::: "memory");
          const int ok = (lane >= 8) || (v >= (unsigned)(s + 1));
          if (__all(ok)) break;
          __builtin_amdgcn_s_sleep(1);
        }
      }
      __syncthreads();
#pragma unroll
      for (int j = 0; j < 4; ++j) { xr[j] = nxr[j]; xz[j] = nxz[j]; xn[j] = nxn[j]; }
    } else {
#pragma unroll
      for (int j = 0; j < 4; ++j) {
        const int b = (ib << 4) + (lk << 2) + j;
        if (out_seq) out_seq[((size_t)(b * S + xidx) << 9) + col] = hn4[j];
        if (gru == 2) qbuf[((size_t)b << 9) + col] = hn4[j];
      }
    }
  }
}

// ---------------------------------------------------------------------------
// MFMA persistent AGRU scan (round-13 proven, unchanged). 32 WGs.
// ---------------------------------------------------------------------------
__global__ __launch_bounds__(256, 1) void k_agru_scan_mfma(
    const float* __restrict__ UrT, const float* __restrict__ UT,
    const float* __restrict__ fRW, const float* __restrict__ fW,
    const float* __restrict__ br, const float* __restrict__ G,
    ushort_t* __restrict__ C16, float* __restrict__ C0f,
    unsigned* __restrict__ flags_base) {
  const int bx   = blockIdx.x;     // 32
  const int grp  = bx >> 3;        // 0..3 (16 items each)
  const int rank = bx & 7;
  ushort_t* Cb0 = C16;
  ushort_t* Cb1 = C16 + 32768;

  __shared__ __align__(16) ushort_t cl[16 * 520];

  const int t    = threadIdx.x;
  const int lane = t & 63;
  const int wv   = t >> 6;
  const int nt   = (rank << 2) + wv;
  const int lm   = lane & 15;
  const int lk   = lane >> 4;
  const int col  = (nt << 4) + lm;

  bf16x8 wfr[16], wfu[16];
  {
    const float* r0 = UrT + ((size_t)col << 9) + (lk << 3);
    const float* r1 = UT  + ((size_t)col << 9) + (lk << 3);
#pragma unroll
    for (int ks = 0; ks < 16; ++ks) {
      wfr[ks] = pack8(*(const f32x4*)(r0 + ks * 32), *(const f32x4*)(r0 + ks * 32 + 4));
      wfu[ks] = pack8(*(const f32x4*)(r1 + ks * 32), *(const f32x4*)(r1 + ks * 32 + 4));
    }
  }
  const float brv = br[col];
  unsigned* flags = flags_base + grp * 8 * 32;

  float fr[4], fw[4], gg[4];
#pragma unroll
  for (int j = 0; j < 4; ++j) {
    const int b = (grp << 4) + (lk << 2) + j;
    const size_t fi = ((size_t)(b * S) << 9) + col;
    fr[j] = fRW[fi];
    fw[j] = fW[fi];
    gg[j] = G[b << 6];
  }

  float cp[4] = {0.f, 0.f, 0.f, 0.f};

  for (int s = 0; s < S; ++s) {
    if (s == 0) {
      for (int i = t; i < 4160; i += 256) ((unsigned*)cl)[i] = 0u;
    } else {
      const ushort_t* Cp16 = (s & 1) ? Cb1 : Cb0;
      u32x4 v[4];
#pragma unroll
      for (int u = 0; u < 4; ++u) {
        const int i = (u << 8) + t;
        v[u] = ld16c(Cp16 + ((size_t)((grp << 4) + (i >> 6)) << 9) + ((i << 3) & 511));
      }
      waitvm0();
#pragma unroll
      for (int u = 0; u < 4; ++u) {
        const int i = (u << 8) + t;
        *(u32x4*)&cl[(i >> 6) * 520 + ((i << 3) & 511)] = v[u];
      }
    }
    __syncthreads();

    f32x4 accr = {}, accu = {};
#pragma unroll
    for (int ks = 0; ks < 16; ++ks) {
      const bf16x8 a = *(const bf16x8*)&cl[lm * 520 + (ks << 5) + (lk << 3)];
      accr = __builtin_amdgcn_mfma_f32_16x16x32_bf16(a, wfr[ks], accr, 0, 0, 0);
      accu = __builtin_amdgcn_mfma_f32_16x16x32_bf16(a, wfu[ks], accu, 0, 0, 0);
    }

    ushort_t* Cn16 = (s & 1) ? Cb0 : Cb1;
    float cn4[4];
#pragma unroll
    for (int j = 0; j < 4; ++j) {
      const int b = (grp << 4) + (lk << 2) + j;
      const float r  = sigm(fr[j] + accr[j] + brv);
      const float ht = tanhf(fw[j] + r * accu[j] + brv);
      const float cnew = gg[j] * ht + (1.f - gg[j]) * cp[j];
      cp[j] = cnew;
      cn4[j] = cnew;
      if (s + 1 < S) st2c(Cn16 + ((size_t)b << 9) + col, (unsigned)f2bf(cnew));
    }

    if (s + 1 < S) {
      waitvm0();
      __syncthreads();
      if (t == 0) stflag(flags + rank * 32, (unsigned)(s + 1));
      float nfr[4], nfw[4], ngg[4];
#pragma unroll
      for (int j = 0; j < 4; ++j) {
        const int b = (grp << 4) + (lk << 2) + j;
        const size_t fi = ((size_t)(b * S + s + 1) << 9) + col;
        nfr[j] = fRW[fi];
        nfw[j] = fW[fi];
        ngg[j] = G[(b << 6) + s + 1];
      }
      if (wv == 0) {
        const unsigned* fp = flags + (lane & 7) * 32;
        for (;;) {
          const unsigned v = ldflag(fp);
          asm volatile("s_waitcnt vmcnt(0)" ::: "memory");
          const int ok = (lane >= 8) || (v >= (unsigned)(s + 1));
          if (__all(ok)) break;
          __builtin_amdgcn_s_sleep(1);
        }
      }
      __syncthreads();
#pragma unroll
      for (int j = 0; j < 4; ++j) { fr[j] = nfr[j]; fw[j] = nfw[j]; gg[j] = ngg[j]; }
    } else {
#pragma unroll
      for (int j = 0; j < 4; ++j) {
        const int b = (grp << 4) + (lk << 2) + j;
        C0f[((size_t)b << 9) + col] = cn4[j];
      }
    }
  }
}

__global__ __launch_bounds__(256) void k_add(float* __restrict__ a, const float* __restrict__ b) {
  const size_t i = (((size_t)blockIdx.x << 8) + threadIdx.x) << 2;
  float4 x = *(float4*)(a + i);
  const float4 y = *(const float4*)(b + i);
  x.x += y.x; x.y += y.y; x.z += y.z; x.w += y.w;
  *(float4*)(a + i) = x;
}

__global__ __launch_bounds__(256) void k_score_softmax(const float* __restrict__ g1,
                                                       const float* __restrict__ z2w,
                                                       const float* __restrict__ z2b,
                                                       float* __restrict__ G) {
  const int b = blockIdx.x, t = threadIdx.x;
  const int wave = t >> 6, lane = t & 63;
  __shared__ float sc[64];
  for (int si = 0; si < 16; ++si) {
    const int s = wave * 16 + si;
    const float* row = g1 + ((size_t)(b * S + s) << 9) + lane * 8;
    const float* w   = z2w + lane * 8;
    float p = 0.f;
#pragma unroll
    for (int k = 0; k < 8; ++k) p += row[k] * w[k];
#pragma unroll
    for (int off = 32; off; off >>= 1) p += __shfl_xor(p, off);
    if (lane == 0) sc[s] = p + z2b[0];
  }
  __syncthreads();
  if (wave == 0) {
    const float v = sc[lane];
    float m = v;
#pragma unroll
    for (int off = 32; off; off >>= 1) m = fmaxf(m, __shfl_xor(m, off));
    const float e = expf(v - m);
    float su = e;
#pragma unroll
    for (int off = 32; off; off >>= 1) su += __shfl_xor(su, off);
    G[(b << 6) + lane] = e / su;
  }
}

}  // namespace

extern "C" void kernel_launch(void* const* d_in, const int* in_sizes, int n_in,
                              void* d_out, int out_size, void* d_ws, size_t ws_size,
                              hipStream_t stream) {
  const int*   contexts  = (const int*)d_in[0];
  const int*   questions = (const int*)d_in[1];
  const float* emb   = (const float*)d_in[2];
  const float* Wih_f = (const float*)d_in[3];
  const float* Whh_f = (const float*)d_in[4];
  const float* bih_f = (const float*)d_in[5];
  const float* bhh_f = (const float*)d_in[6];
  const float* Wih_b = (const float*)d_in[7];
  const float* Whh_b = (const float*)d_in[8];
  const float* bih_b = (const float*)d_in[9];
  const float* bhh_b = (const float*)d_in[10];
  const float* qWih  = (const float*)d_in[11];
  const float* qWhh  = (const float*)d_in[12];
  const float* qbih  = (const float*)d_in[13];
  const float* qbhh  = (const float*)d_in[14];
  const float* Wr    = (const float*)d_in[15];
  const float* Ur    = (const float*)d_in[16];
  const float* br    = (const float*)d_in[17];
  const float* Wm    = (const float*)d_in[18];
  const float* Um    = (const float*)d_in[19];
  const float* z1_w  = (const float*)d_in[20];
  const float* z1_b  = (const float*)d_in[21];
  const float* z2_w  = (const float*)d_in[22];
  const float* z2_b  = (const float*)d_in[23];
  const float* nm_w  = (const float*)d_in[24];
  const float* nm_b  = (const float*)d_in[25];
  const float* ans_w = (const float*)d_in[26];
  const float* ans_b = (const float*)d_in[27];
  (void)in_sizes; (void)n_in; (void)out_size; (void)ws_size;

  float* ws = (float*)d_ws;
  float* WrT      = ws + 0;          // 262144
  float* UrT      = ws + 262144;     // 262144
  float* WT       = ws + 524288;     // 262144
  float* UT       = ws + 786432;     // 262144
  float* facts_in = ws + 1048576;    // 2097152  (reused as fRW)
  float* qe       = ws + 3145728;    // 1048576
  float* gx_f     = ws + 4194304;    // 6291456  (post-scan: zq16|zm16|g1q, exact fit)
  float* gx_b     = ws + 10485760;   // 6291456  (post-scan: Bq|Bmw)
  float* gx_q     = ws + 16777216;   // 3145728  (reused as g1)
  float* facts    = ws + 19922944;   // 2097152
  float* hb       = ws + 22020096;   // 2097152  (reused as fW)
  float* Hbuf     = ws + 24117248;   // 196608: H16/q/C16
  float* C0       = ws + 24313856;   // 32768 (final AGRU state, f32)
  float* M0       = ws + 24379392;   // 32768
  float* M1       = ws + 24412160;   // 32768
  float* Mq       = ws + 24543232;   // flags region
  float* Gm       = ws + 24608768;   // 4096
  ushort_t* H16 = (ushort_t*)Hbuf;             // 3 GRUs x 2 x [64][512] bf16
  float* qbuf   = Hbuf + 98304;                // 32768 floats (question state)
  ushort_t* C16 = (ushort_t*)(Hbuf + 131072);  // 2 x [64][512] bf16
  // post-scan reuse (FIXED round-14 overlap bug):
  //   zq16: 4096x1024 bf16 = 2097152 floats  @ gx_f + 0
  //   zm16: 4096x1024 bf16 = 2097152 floats  @ gx_f + 2097152
  //   g1q : 4096x512  f32  = 2097152 floats  @ gx_f + 4194304  (exact fit)
  //   Bq  : 512x1024  f32  =  524288 floats  @ gx_b + 0
  //   Bmw : 512x1024  f32  =  524288 floats  @ gx_b + 524288
  ushort_t* zq16 = (ushort_t*)gx_f;
  ushort_t* zm16 = (ushort_t*)(gx_f + 2097152);
  float* g1q = gx_f + 4194304;
  float* Bq  = gx_b;
  float* Bmw = gx_b + 524288;
  float* g1  = gx_q;
  float* fRW = facts_in;
  float* fW  = hb;
  float* preds = (float*)d_out;
  unsigned* bar = (unsigned*)Mq;     // flags: GRU 12*256 + 3 hops * 4*256 = 6144 u32
  float* q = qbuf;

  // ---- flags: zero once per call (monotone counters) ----
  hipMemsetAsync(bar, 0, 6144 * sizeof(unsigned), stream);

  // ---- stage A: embeddings + weight transposes ----
  k_embed_facts<<<B * S, 256, 0, stream>>>(contexts, emb, facts_in);
  k_embed_q<<<B * TQ, 256, 0, stream>>>(questions, emb, qe);
  dim3 tb(32, 8);
  k_transpose512<<<dim3(16, 16), tb, 0, stream>>>(Wr, WrT);
  k_transpose512<<<dim3(16, 16), tb, 0, stream>>>(Ur, UrT);
  k_transpose512<<<dim3(16, 16), tb, 0, stream>>>(Wm, WT);
  k_transpose512<<<dim3(16, 16), tb, 0, stream>>>(Um, UT);

  // ---- stage B: merged gate GEMMs (one launch) ----
  k_gemm_b3<<<dim3(24, 160), 256, 0, stream>>>(facts_in, qe, Wih_f, bih_f,
                                               Wih_b, bih_b, qWih, qbih,
                                               gx_f, gx_b, gx_q);

  // ---- stage C: MFMA persistent GRU scans (plain launch, 96 WGs) ----
  k_gru_scan_mfma<<<96, 256, 0, stream>>>(Whh_f, bhh_f, Whh_b, bhh_b, qWhh, qbhh,
                                          gx_f, gx_b, gx_q, H16, qbuf, facts, hb, bar);
  k_add<<<2048, 256, 0, stream>>>(facts, hb);

  // ---- stage D: hop-invariant precomputes ----
  k_split_z1w<<<512, 256, 0, stream>>>(z1_w, Bq, Bmw);
  k_build_zq16<<<B * S, 256, 0, stream>>>(facts, q, zq16);
  k_gemm_d2<<<dim3(8, 128), 256, 0, stream>>>(facts, WrT, WT, fRW, fW);
  k_gemm_mfma<true, 0, false><<<dim3(8, 64), 256, 0, stream>>>(zq16, Bq, nullptr, g1q,
                                                               4096, 512, 1024, nullptr);

  // ---- stage E: episodic memory hops (z1 = q-part + M-part) ----
  const float* Mcur = q;
  for (int h = 0; h < 3; ++h) {
    k_build_zm16<<<B * S, 256, 0, stream>>>(facts, Mcur, zm16);
    k_gemm_mfma<true, 1, true><<<dim3(8, 64), 256, 0, stream>>>(zm16, Bmw, z1_b, g1,
                                                                4096, 512, 1024, g1q);
    k_score_softmax<<<B, 256, 0, stream>>>(g1, z2_w, z2_b, Gm);
    unsigned* fl = bar + 3072 + h * 1024;
    k_agru_scan_mfma<<<32, 256, 0, stream>>>(UrT, UT, fRW, fW, br, Gm, C16, C0, fl);
    float* Mnext = (h & 1) ? M1 : M0;
    k_gemm_cat3<<<dim3(8, 1), 256, 0, stream>>>(Mcur, C0, q, nm_w, nm_b, Mnext);
    Mcur = Mnext;
  }

  // ---- stage F: answer projection (fused concat2) ----
  k_gemm_cat2<<<dim3(500, 1), 256, 0, stream>>>(Mcur, q, ans_w, ans_b, preds);
}